// Round 2
// baseline (1753.645 us; speedup 1.0000x reference)
//
#include <hip/hip_runtime.h>
#include <cmath>
#include <complex>
#include <algorithm>

#define N_NODES  32768
#define FEAT_DIM 480
#define TMUL     224
#define NB       4
#define ST       3328   // per-node LDS stride (floats)

// per-node LDS offsets (floats)
#define F0O 0
#define F1O 128
#define F2O 320
#define P0O 480
#define P1O 608
#define P2O 800
#define C0O 960
#define C1O 1184
#define C2O 2048
// Q (post-linear out) overlays C0/C1-head: written only after all C reads done
#define Q0O 960
#define Q1O 1088
#define Q2O 1280
// normgate scratch overlays C1/C2-head: only live while C is dead
#define INVO 1440
#define HO   1664
#define GO   1888
#define REDO 2112

// workspace layout (floats): transposed / regrouped weights, scales folded
#define WSA   0        // 28672  wtA[r*128+v]   (group A t-weights, row-major)
#define WSB   28672    // 18432  wtB[r*64+v]
#define WSC   47104    // 8192   wtC[r*32+v]
#define W0T   55296    // 16384  w0T[c*128+u]  * 1/sqrt(128)
#define W1T   71680    // 4096   w1T[c*64+u]   * 1/8
#define W2T   75776    // 1024   w2T[c*32+u]   * 1/sqrt(32)
#define PGW1T 76800    // 50176  pgw1T[c*224+u]
#define PGW2T 126976   // 50176
#define PW0T  177152   // 28672  pw0T[c*224+u] * 1/sqrt(224)
#define PW1T  205824   // 18432  pw1T[c*288+u] * 1/sqrt(288)
#define PW2T  224256   // 8192   pw2T[c*256+u] * 1/16
#define QGW1T 232448   // 50176
#define QGW2T 282624   // 50176  -> total 332800 floats (1.33 MB)
#define WS_TOTAL 332800

typedef float f32x4 __attribute__((ext_vector_type(4)));

__device__ __forceinline__ float siluf(float x){ return x * (1.0f/(1.0f + __expf(-x))); }
__device__ __forceinline__ float hsum4(f32x4 a){ return (a.x+a.y)+(a.z+a.w); }

struct W3Pack { float v[363]; };

// ------------------------- host: exact Wigner-3j (mirrors reference) -------------------------
static double factd(int n){ double f=1.0; for(int i=2;i<=n;++i) f*=(double)i; return f; }

static double su2_cg(int j1,int j2,int j3,int m1,int m2,int m3){
  if (m1+m2 != m3) return 0.0;
  double pref = std::sqrt((2.0*j3+1.0)*factd(j3+j1-j2)*factd(j3-j1+j2)*factd(j1+j2-j3)/factd(j1+j2+j3+1));
  pref *= std::sqrt(factd(j3+m3)*factd(j3-m3)*factd(j1-m1)*factd(j1+m1)*factd(j2-m2)*factd(j2+m2));
  double s=0.0;
  int vmin = std::max(0, std::max(j2-j3-m1, j1-j3+m2));
  int vmax = std::min(j2+m2, std::min(j1-m1, j1+j2-j3));
  for (int v=vmin; v<=vmax; ++v){
    double d = factd(v)*factd(j1+j2-j3-v)*factd(j1-m1-v)*factd(j2+m2-v)*factd(j3-j2+m1+v)*factd(j3-j1-m2+v);
    s += ((v&1)? -1.0 : 1.0)/d;
  }
  return pref*s;
}

typedef std::complex<double> cd;

static void qmat(int l, cd* q){
  int d=2*l+1;
  for (int a=0;a<d*d;++a) q[a]=cd(0,0);
  double is2 = 1.0/std::sqrt(2.0);
  for (int m=-l; m<0; ++m){
    int am=-m;
    q[(l+m)*d + (l+am)] = cd(is2,0);
    q[(l+m)*d + (l-am)] = cd(0,-is2);
  }
  q[l*d+l] = cd(1,0);
  for (int m=1;m<=l;++m){
    double sg = (m&1)? -1.0:1.0;
    q[(l+m)*d + (l+m)] = cd(sg*is2,0);
    q[(l+m)*d + (l-m)] = cd(0,sg*is2);
  }
  cd f = (l==0)? cd(1,0) : (l==1? cd(0,-1) : cd(-1,0)); // (-i)^l for l<=2
  for (int a=0;a<d*d;++a) q[a]*=f;
}

static void wigner3j(int l1,int l2,int l3, float* out){
  int d1=2*l1+1,d2=2*l2+1,d3=2*l3+1;
  double Cc[5][5][5] = {};
  for (int m1=-l1;m1<=l1;++m1) for (int m2=-l2;m2<=l2;++m2){
    int m3=m1+m2;
    if (m3>=-l3 && m3<=l3) Cc[l1+m1][l2+m2][l3+m3] = su2_cg(l1,l2,l3,m1,m2,m3);
  }
  cd q1[25],q2[25],q3[25];
  qmat(l1,q1); qmat(l2,q2); qmat(l3,q3);
  double re[125], im[125];
  double nr=0, ni=0;
  for (int i=0;i<d1;++i) for (int j=0;j<d2;++j) for (int k=0;k<d3;++k){
    cd s(0,0);
    for (int a=0;a<d1;++a) for (int b=0;b<d2;++b) for (int c=0;c<d3;++c){
      double cc = Cc[a][b][c];
      if (cc != 0.0) s += q1[a*d1+i]*q2[b*d2+j]*std::conj(q3[c*d3+k])*cc;
    }
    int o=(i*d2+j)*d3+k;
    re[o]=s.real(); im[o]=s.imag();
    nr += s.real()*s.real(); ni += s.imag()*s.imag();
  }
  bool useRe = std::sqrt(nr) >= std::sqrt(ni);
  double nrm = std::sqrt(useRe? nr : ni);
  for (int o=0;o<d1*d2*d3;++o) out[o] = (float)((useRe? re[o] : im[o]) / nrm);
}

static W3Pack build_w3(){
  W3Pack W;
  wigner3j(0,0,0, W.v+0);
  wigner3j(0,1,1, W.v+1);
  wigner3j(0,2,2, W.v+10);
  wigner3j(1,0,1, W.v+35);
  wigner3j(1,1,0, W.v+44);
  wigner3j(1,1,2, W.v+53);
  wigner3j(1,2,1, W.v+98);
  wigner3j(2,0,2, W.v+143);
  wigner3j(2,1,1, W.v+168);
  wigner3j(2,2,0, W.v+213);
  wigner3j(2,2,2, W.v+238);
  return W;
}

// ------------------------- device: weight transpose/regroup into ws -------------------------
__global__ __launch_bounds__(256) void prep_w(
  const float* __restrict__ tpw,
  const float* __restrict__ w0, const float* __restrict__ w1, const float* __restrict__ w2,
  const float* __restrict__ pgw1, const float* __restrict__ pgw2,
  const float* __restrict__ pw0, const float* __restrict__ pw1, const float* __restrict__ pw2,
  const float* __restrict__ qgw1, const float* __restrict__ qgw2,
  float* __restrict__ ws)
{
  const int t = blockIdx.x*256 + threadIdx.x;
  if (t >= WS_TOTAL) return;
  float val;
  if (t < WSB) {                                  // wtA: [224 rows][128 v]
    const int r = t >> 7, v = t & 127;
    int off, u;
    if (r < 128)      { off = 0;     u = r; }
    else if (r < 192) { off = 28672; u = r-128; }
    else              { off = 47104; u = r-192; }
    val = tpw[off + u*128 + v] * 0.08838834764831845f;
  } else if (t < WSC) {                           // wtB: [288 rows][64 v]
    const int s = t - WSB; const int r = s >> 6, v = s & 63;
    int off, u;
    if (r < 128)      { off = 16384; u = r; }
    else if (r < 192) { off = 36864; u = r-128; }
    else if (r < 256) { off = 40960; u = r-192; }
    else              { off = 51200; u = r-256; }
    val = tpw[off + u*64 + v] * 0.125f;
  } else if (t < W0T) {                           // wtC: [256 rows][32 v]
    const int s = t - WSC; const int r = s >> 5, v = s & 31;
    int off, u;
    if (r < 128)      { off = 24576; u = r; }
    else if (r < 192) { off = 45056; u = r-128; }
    else if (r < 224) { off = 53248; u = r-192; }
    else              { off = 54272; u = r-224; }
    val = tpw[off + u*32 + v] * 0.17677669529663687f;
  } else if (t < W1T) {                           // w0T[c*128+u]
    const int s = t - W0T; const int c = s >> 7, u = s & 127;
    val = w0[u*128 + c] * 0.08838834764831845f;
  } else if (t < W2T) {                           // w1T[c*64+u]
    const int s = t - W1T; const int c = s >> 6, u = s & 63;
    val = w1[u*64 + c] * 0.125f;
  } else if (t < PGW1T) {                         // w2T[c*32+u]
    const int s = t - W2T; const int c = s >> 5, u = s & 31;
    val = w2[u*32 + c] * 0.17677669529663687f;
  } else if (t < PGW2T) {                         // pgw1T[c*224+u]
    const int s = t - PGW1T; const int c = s/224, u = s - c*224;
    val = pgw1[u*224 + c];
  } else if (t < PW0T) {                          // pgw2T
    const int s = t - PGW2T; const int c = s/224, u = s - c*224;
    val = pgw2[u*224 + c];
  } else if (t < PW1T) {                          // pw0T[c*224+u], pw0 [224][128]
    const int s = t - PW0T; const int c = s/224, u = s - c*224;
    val = pw0[u*128 + c] * 0.06681531047810609f;
  } else if (t < PW2T) {                          // pw1T[c*288+u], pw1 [288][64]
    const int s = t - PW1T; const int c = s/288, u = s - c*288;
    val = pw1[u*64 + c] * 0.05892556509887896f;
  } else if (t < QGW1T) {                         // pw2T[c*256+u], pw2 [256][32]
    const int s = t - PW2T; const int c = s >> 8, u = s & 255;
    val = pw2[u*32 + c] * 0.0625f;
  } else if (t < QGW2T) {                         // qgw1T
    const int s = t - QGW1T; const int c = s/224, u = s - c*224;
    val = qgw1[u*224 + c];
  } else {                                        // qgw2T
    const int s = t - QGW2T; const int c = s/224, u = s - c*224;
    val = qgw2[u*224 + c];
  }
  ws[t] = val;
}

// ------------------------- column matvec, transposed weights, packed f32 -------------------------
// WT row-contiguous per column: wp = WT + col*N; acc4 += x4*w4 -> v_pk_fma_f32 pairs
template<int N>
__device__ __forceinline__ void matcolT(const float* __restrict__ WT, const int col,
                                        const float* __restrict__ Lp, const int inbase,
                                        float (&out)[NB])
{
  f32x4 acc[NB] = {};
  const f32x4* __restrict__ wp = (const f32x4*)(WT + (size_t)col*N);
  #pragma unroll 4
  for (int u4=0; u4<N/4; ++u4) {
    const f32x4 w = wp[u4];
    #pragma unroll
    for (int nb=0;nb<NB;++nb) {
      const f32x4 x = *(const f32x4*)(Lp + nb*ST + inbase + u4*4);
      acc[nb] += x*w;
    }
  }
  #pragma unroll
  for (int nb=0;nb<NB;++nb) out[nb] = hsum4(acc[nb]);
}

// t-stage for CG: NJ components share one weight row (M2 long), jstep between components
template<int NJ, int M2, int JS>
__device__ __forceinline__ void tstageT(const float* __restrict__ wrow,
                                        const float* __restrict__ L, const int pbase,
                                        float (&t)[NJ][NB])
{
  f32x4 acc[NJ][NB] = {};
  const f32x4* __restrict__ wp = (const f32x4*)wrow;
  #pragma unroll 2
  for (int v4=0; v4<M2/4; ++v4) {
    const f32x4 w = wp[v4];
    #pragma unroll
    for (int j=0;j<NJ;++j) {
      #pragma unroll
      for (int nb=0;nb<NB;++nb) {
        const f32x4 x = *(const f32x4*)(L + nb*ST + pbase + j*JS + v4*4);
        acc[j][nb] += x*w;
      }
    }
  }
  #pragma unroll
  for (int j=0;j<NJ;++j)
    #pragma unroll
    for (int nb=0;nb<NB;++nb) t[j][nb] = hsum4(acc[j][nb]);
}

// ------------------------- normgate (inv -> wave-parallel mean/var -> MLP -> G) -------------------------
__device__ __forceinline__ void normgate(float* __restrict__ L, const int c,
                                         const int B0, const int B1, const int B2,
                                         const float* __restrict__ gw1T, const float* __restrict__ gb1,
                                         const float* __restrict__ gw2T, const float* __restrict__ gb2)
{
  if (c < 128) {
    #pragma unroll
    for (int nb=0;nb<NB;++nb) L[nb*ST+INVO+c] = L[nb*ST+B0+c];
  } else if (c < 192) {
    const int v = c-128;
    #pragma unroll
    for (int nb=0;nb<NB;++nb) {
      float s = 1e-12f;
      #pragma unroll
      for (int i=0;i<3;++i){ const float x = L[nb*ST+B1+i*64+v]; s += x*x; }
      L[nb*ST+INVO+c] = sqrtf(s);
    }
  } else if (c < 224) {
    const int v = c-192;
    #pragma unroll
    for (int nb=0;nb<NB;++nb) {
      float s = 1e-12f;
      #pragma unroll
      for (int i=0;i<5;++i){ const float x = L[nb*ST+B2+i*32+v]; s += x*x; }
      L[nb*ST+INVO+c] = sqrtf(s);
    }
  }
  __syncthreads();
  {
    const int w = c>>6, l = c&63;   // wave w <-> node w
    float s=0.f, s2=0.f, x;
    x = L[w*ST+INVO+l];     s+=x; s2+=x*x;
    x = L[w*ST+INVO+64+l];  s+=x; s2+=x*x;
    x = L[w*ST+INVO+128+l]; s+=x; s2+=x*x;
    if (l < 32) { x = L[w*ST+INVO+192+l]; s+=x; s2+=x*x; }
    #pragma unroll
    for (int off=32; off>=1; off>>=1) {
      s  += __shfl_xor(s,  off, 64);
      s2 += __shfl_xor(s2, off, 64);
    }
    if (l==0) {
      const float m = s*(1.f/224.f);
      L[w*ST+REDO+0] = m;
      L[w*ST+REDO+1] = rsqrtf(s2*(1.f/224.f) - m*m + 1e-5f);
    }
  }
  __syncthreads();
  if (c < TMUL) {
    #pragma unroll
    for (int nb=0;nb<NB;++nb)
      L[nb*ST+INVO+c] = (L[nb*ST+INVO+c]-L[nb*ST+REDO+0])*L[nb*ST+REDO+1];
  }
  __syncthreads();
  if (c < TMUL) {
    float acc[NB];
    matcolT<224>(gw1T, c, L, INVO, acc);
    const float b = gb1[c];
    #pragma unroll
    for (int nb=0;nb<NB;++nb) L[nb*ST+HO+c] = siluf(acc[nb]+b);
  }
  __syncthreads();
  if (c < TMUL) {
    float acc[NB];
    matcolT<224>(gw2T, c, L, HO, acc);
    const float b = gb2[c];
    #pragma unroll
    for (int nb=0;nb<NB;++nb) L[nb*ST+GO+c] = siluf(acc[nb]+b);
  }
  // no trailing sync: thread c's G[*][c] is self-written; callers sync before cross-thread G reads
}

// ------------------------- CG rows, groups B and C (t in regs, fused y) -------------------------
__device__ __forceinline__ void cg_rowB(const int r, const float* __restrict__ ws,
                                        const W3Pack& W, float* __restrict__ L)
{
  float tb[3][NB];
  tstageT<3,64,64>(ws + WSB + r*64, L, P1O, tb);
  if (r < 128) {                       // p2 (0,1,1): out C1 row r
    #pragma unroll
    for (int nb=0;nb<NB;++nb) {
      const float f = L[nb*ST+F0O+r];
      #pragma unroll
      for (int k=0;k<3;++k) {
        float s=0.f;
        #pragma unroll
        for (int j=0;j<3;++j) s += tb[j][nb]*W.v[1+j*3+k];
        L[nb*ST+C1O+k*288+r] = f*s;
      }
    }
  } else if (r < 192) {                // p5 (1,1,0): out C0 row 128+u
    const int u=r-128;
    #pragma unroll
    for (int nb=0;nb<NB;++nb) {
      float y=0.f;
      #pragma unroll
      for (int i=0;i<3;++i) {
        float s=0.f;
        #pragma unroll
        for (int j=0;j<3;++j) s += tb[j][nb]*W.v[44+i*3+j];
        y += L[nb*ST+F1O+i*64+u]*s;
      }
      L[nb*ST+C0O+128+u] = y;
    }
  } else if (r < 256) {                // p6 (1,1,2): out C2 row 128+u
    const int u=r-192;
    #pragma unroll
    for (int nb=0;nb<NB;++nb) {
      float f[3];
      #pragma unroll
      for (int i=0;i<3;++i) f[i]=L[nb*ST+F1O+i*64+u];
      #pragma unroll
      for (int k=0;k<5;++k) {
        float y=0.f;
        #pragma unroll
        for (int i=0;i<3;++i) {
          float s=0.f;
          #pragma unroll
          for (int j=0;j<3;++j) s += tb[j][nb]*W.v[53+(i*3+j)*5+k];
          y += f[i]*s;
        }
        L[nb*ST+C2O+k*256+128+u] = y;
      }
    }
  } else {                             // p9 (2,1,1): out C1 row 256+u
    const int u=r-256;
    #pragma unroll
    for (int nb=0;nb<NB;++nb) {
      float f[5];
      #pragma unroll
      for (int i=0;i<5;++i) f[i]=L[nb*ST+F2O+i*32+u];
      #pragma unroll
      for (int k=0;k<3;++k) {
        float y=0.f;
        #pragma unroll
        for (int i=0;i<5;++i) {
          float s=0.f;
          #pragma unroll
          for (int j=0;j<3;++j) s += tb[j][nb]*W.v[168+(i*3+j)*3+k];
          y += f[i]*s;
        }
        L[nb*ST+C1O+k*288+256+u] = y;
      }
    }
  }
}

__device__ __forceinline__ void cg_rowC(const int r, const float* __restrict__ ws,
                                        const W3Pack& W, float* __restrict__ L)
{
  float tc[5][NB];
  {
    float tp[3][NB];
    tstageT<3,32,32>(ws + WSC + r*32, L, P2O, tp);
    #pragma unroll
    for (int j=0;j<3;++j)
      #pragma unroll
      for (int nb=0;nb<NB;++nb) tc[j][nb]=tp[j][nb];
  }
  {
    float tp[2][NB];
    tstageT<2,32,32>(ws + WSC + r*32, L, P2O+96, tp);
    #pragma unroll
    for (int nb=0;nb<NB;++nb) { tc[3][nb]=tp[0][nb]; tc[4][nb]=tp[1][nb]; }
  }
  if (r < 128) {                       // p3 (0,2,2): out C2 row r
    #pragma unroll
    for (int nb=0;nb<NB;++nb) {
      const float f = L[nb*ST+F0O+r];
      #pragma unroll
      for (int k=0;k<5;++k) {
        float s=0.f;
        #pragma unroll
        for (int j=0;j<5;++j) s += tc[j][nb]*W.v[10+j*5+k];
        L[nb*ST+C2O+k*256+r] = f*s;
      }
    }
  } else if (r < 192) {                // p7 (1,2,1): out C1 row 192+u
    const int u=r-128;
    #pragma unroll
    for (int nb=0;nb<NB;++nb) {
      float f[3];
      #pragma unroll
      for (int i=0;i<3;++i) f[i]=L[nb*ST+F1O+i*64+u];
      #pragma unroll
      for (int k=0;k<3;++k) {
        float y=0.f;
        #pragma unroll
        for (int i=0;i<3;++i) {
          float s=0.f;
          #pragma unroll
          for (int j=0;j<5;++j) s += tc[j][nb]*W.v[98+(i*5+j)*3+k];
          y += f[i]*s;
        }
        L[nb*ST+C1O+k*288+192+u] = y;
      }
    }
  } else if (r < 224) {                // p10 (2,2,0): out C0 row 192+u
    const int u=r-192;
    #pragma unroll
    for (int nb=0;nb<NB;++nb) {
      float y=0.f;
      #pragma unroll
      for (int i=0;i<5;++i) {
        float s=0.f;
        #pragma unroll
        for (int j=0;j<5;++j) s += tc[j][nb]*W.v[213+i*5+j];
        y += L[nb*ST+F2O+i*32+u]*s;
      }
      L[nb*ST+C0O+192+u] = y;
    }
  } else {                             // p11 (2,2,2): out C2 row 224+u
    const int u=r-224;
    #pragma unroll
    for (int nb=0;nb<NB;++nb) {
      float f[5];
      #pragma unroll
      for (int i=0;i<5;++i) f[i]=L[nb*ST+F2O+i*32+u];
      #pragma unroll
      for (int k=0;k<5;++k) {
        float y=0.f;
        #pragma unroll
        for (int i=0;i<5;++i) {
          float s=0.f;
          #pragma unroll
          for (int j=0;j<5;++j) s += tc[j][nb]*W.v[238+(i*5+j)*5+k];
          y += f[i]*s;
        }
        L[nb*ST+C2O+k*256+224+u] = y;
      }
    }
  }
}

// ------------------------- fused kernel: NB nodes per block -------------------------
__global__ __launch_bounds__(256, 3) void fused4(
  const float* __restrict__ feat,
  const float* __restrict__ ws,
  const float* __restrict__ pgb1, const float* __restrict__ pgb2,
  const float* __restrict__ qgb1, const float* __restrict__ qgb2,
  float* __restrict__ outp, const W3Pack W)
{
  __shared__ float L[ST*NB];
  const int c = threadIdx.x;
  const size_t gbase = (size_t)blockIdx.x * (FEAT_DIM*NB);

  // ---- load + de-interleave (component-major F blocks) ----
  for (int t=c; t<FEAT_DIM*NB; t+=256) {
    const float val = feat[gbase + t];
    const int nb = t / FEAT_DIM;
    const int ch = t - nb*FEAT_DIM;
    int loc;
    if (ch < 128) loc = F0O + ch;
    else if (ch < 320) { const int q = ch-128; const int u = q/3; loc = F1O + (q-u*3)*64 + u; }
    else               { const int q = ch-320; const int u = q/5; loc = F2O + (q-u*5)*32 + u; }
    L[nb*ST + loc] = val;
  }
  __syncthreads();

  // ---- pre-linear (slot-balanced; scales folded into transposed weights) ----
  {
    float a1[NB], a2[NB];
    int o1, o2=-1;
    if (c < 128) { matcolT<128>(ws+W0T, c, L, F0O, a1); o1 = P0O+c; }
    else { const int q=c-128; const int i=q>>6, v=q&63;
           matcolT<64>(ws+W1T, v, L, F1O+i*64, a1); o1 = P1O+i*64+v; }
    if (c < 64) { matcolT<64>(ws+W1T, c, L, F1O+128, a2); o2 = P1O+128+c; }
    else if (c < 224) { const int q=c-64; const int i=q>>5, v=q&31;
           matcolT<32>(ws+W2T, v, L, F2O+i*32, a2); o2 = P2O+i*32+v; }
    #pragma unroll
    for (int nb=0;nb<NB;++nb) L[nb*ST + o1] = a1[nb];
    if (o2 >= 0) {
      #pragma unroll
      for (int nb=0;nb<NB;++nb) L[nb*ST + o2] = a2[nb];
    }
  }
  __syncthreads();

  // ---- pre normgate + gate P in place ----
  normgate(L, c, P0O, P1O, P2O, ws+PGW1T, pgb1, ws+PGW2T, pgb2);
  if (c < 128) {
    #pragma unroll
    for (int nb=0;nb<NB;++nb) L[nb*ST+P0O+c] *= L[nb*ST+GO+c];
  } else if (c < 192) {
    const int v=c-128;
    #pragma unroll
    for (int nb=0;nb<NB;++nb) { const float g=L[nb*ST+GO+c];
      #pragma unroll
      for (int i=0;i<3;++i) L[nb*ST+P1O+i*64+v] *= g; }
  } else if (c < 224) {
    const int v=c-192;
    #pragma unroll
    for (int nb=0;nb<NB;++nb) { const float g=L[nb*ST+GO+c];
      #pragma unroll
      for (int i=0;i<5;++i) L[nb*ST+P2O+i*32+v] *= g; }
  }
  __syncthreads();   // P gated; also guarantees all MLP2 H-reads done before CG overwrites scratch

  // ---- CG coupling: group A (thread=row, t in reg, fused y) ----
  if (c < 224) {
    float tA[1][NB];
    tstageT<1,128,0>(ws + WSA + c*128, L, P0O, tA);
    if (c < 128) {                     // p1 (0,0,0): out C0 row c
      #pragma unroll
      for (int nb=0;nb<NB;++nb) L[nb*ST+C0O+c] = L[nb*ST+F0O+c]*tA[0][nb]*W.v[0];
    } else if (c < 192) {              // p4 (1,0,1): out C1 row 128+u
      const int u=c-128;
      #pragma unroll
      for (int nb=0;nb<NB;++nb) {
        const float f0=L[nb*ST+F1O+u], f1=L[nb*ST+F1O+64+u], f2=L[nb*ST+F1O+128+u];
        #pragma unroll
        for (int k=0;k<3;++k)
          L[nb*ST+C1O+k*288+128+u] = tA[0][nb]*(f0*W.v[35+k] + f1*W.v[38+k] + f2*W.v[41+k]);
      }
    } else {                           // p8 (2,0,2): out C2 row 192+u
      const int u=c-192;
      #pragma unroll
      for (int nb=0;nb<NB;++nb) {
        float f[5];
        #pragma unroll
        for (int i=0;i<5;++i) f[i]=L[nb*ST+F2O+i*32+u];
        #pragma unroll
        for (int k=0;k<5;++k) {
          float y=0.f;
          #pragma unroll
          for (int i=0;i<5;++i) y += f[i]*W.v[143+i*5+k];
          L[nb*ST+C2O+k*256+192+u] = tA[0][nb]*y;
        }
      }
    }
  }
  // groups B (288 rows) and C (256 rows)
  cg_rowB(c, ws, W, L);
  if (c >= 224) cg_rowB(c+32, ws, W, L);
  cg_rowC(c, ws, W, L);
  __syncthreads();

  // ---- post-linear (reg-staged: Q overlays C head, write after all C reads) ----
  {
    float pa[NB], pb[NB];
    int po1, po2=-1;
    if (c < 128) { matcolT<224>(ws+PW0T, c, L, C0O, pa); po1 = Q0O+c; }
    else { const int q=c-128; const int i=q>>6, v=q&63;
           matcolT<288>(ws+PW1T, v, L, C1O+i*288, pa); po1 = Q1O+i*64+v; }
    if (c < 64) { matcolT<288>(ws+PW1T, c, L, C1O+2*288, pb); po2 = Q1O+128+c; }
    else if (c < 224) { const int q=c-64; const int i=q>>5, v=q&31;
           matcolT<256>(ws+PW2T, v, L, C2O+i*256, pb); po2 = Q2O+i*32+v; }
    __syncthreads();   // all C reads complete before Q overwrite
    #pragma unroll
    for (int nb=0;nb<NB;++nb) L[nb*ST+po1] = pa[nb];
    if (po2 >= 0) {
      #pragma unroll
      for (int nb=0;nb<NB;++nb) L[nb*ST+po2] = pb[nb];
    }
  }
  __syncthreads();

  // ---- post normgate ----
  normgate(L, c, Q0O, Q1O, Q2O, ws+QGW1T, qgb1, ws+QGW2T, qgb2);
  __syncthreads();   // final reads G cross-thread

  // ---- final: out = feat + pre_gated + post*G (re-interleave, coalesced store) ----
  for (int t=c; t<FEAT_DIM*NB; t+=256) {
    const int nb = t / FEAT_DIM;
    const int ch = t - nb*FEAT_DIM;
    const float* Lb = L + nb*ST;
    float val;
    if (ch < 128) {
      val = Lb[F0O+ch] + Lb[P0O+ch] + Lb[Q0O+ch]*Lb[GO+ch];
    } else if (ch < 320) {
      const int q=ch-128; const int u=q/3; const int o=(q-u*3)*64+u;
      val = Lb[F1O+o] + Lb[P1O+o] + Lb[Q1O+o]*Lb[GO+128+u];
    } else {
      const int q=ch-320; const int u=q/5; const int o=(q-u*5)*32+u;
      val = Lb[F2O+o] + Lb[P2O+o] + Lb[Q2O+o]*Lb[GO+192+u];
    }
    outp[gbase + t] = val;
  }
}

// ------------------------- launch -------------------------
extern "C" void kernel_launch(void* const* d_in, const int* in_sizes, int n_in,
                              void* d_out, int out_size, void* d_ws, size_t ws_size,
                              hipStream_t stream)
{
  (void)in_sizes; (void)n_in; (void)out_size; (void)ws_size;
  const float* feat  = (const float*)d_in[0];
  const float* prw0  = (const float*)d_in[1];
  const float* prw1  = (const float*)d_in[2];
  const float* prw2  = (const float*)d_in[3];
  const float* pngw1 = (const float*)d_in[4];
  const float* pngb1 = (const float*)d_in[5];
  const float* pngw2 = (const float*)d_in[6];
  const float* pngb2 = (const float*)d_in[7];
  const float* tpw   = (const float*)d_in[8];
  const float* pow0  = (const float*)d_in[9];
  const float* pow1  = (const float*)d_in[10];
  const float* pow2  = (const float*)d_in[11];
  const float* qngw1 = (const float*)d_in[12];
  const float* qngb1 = (const float*)d_in[13];
  const float* qngw2 = (const float*)d_in[14];
  const float* qngb2 = (const float*)d_in[15];

  float* ws = (float*)d_ws;            // WS_TOTAL floats: transposed weights

  W3Pack W = build_w3();               // host-only, identical every call

  prep_w<<<dim3((WS_TOTAL+255)/256), dim3(256), 0, stream>>>(
      tpw, prw0, prw1, prw2, pngw1, pngw2, pow0, pow1, pow2, qngw1, qngw2, ws);

  fused4<<<dim3(N_NODES/NB), dim3(256), 0, stream>>>(
      feat, ws, pngb1, pngb2, qngb1, qngb2, (float*)d_out, W);
}

// Round 5
// 1252.197 us; speedup vs baseline: 1.4005x; 1.4005x over previous
//
#include <hip/hip_runtime.h>
#include <cmath>
#include <complex>
#include <algorithm>

#define N_NODES  32768
#define FEAT_DIM 480
#define TMUL     224
#define NB       4
#define ST       3328   // per-node element count; LDS = ST f32x4 entries (node-minor)

// element offsets into L4 (each entry = f32x4 holding 4 nodes)
#define F0O 0
#define F1O 128
#define F2O 320
#define P0O 480
#define P1O 608
#define P2O 800
#define C0O 960
#define C1O 1184
#define C2O 2048
// Q (post-linear out) overlays C0/C1-head: written only after all C reads done
#define Q0O 960
#define Q1O 1088
#define Q2O 1280
// normgate scratch overlays C1-tail/C2-head: only live while C is dead
#define INVO 1440
#define HO   1664
#define GO   1888
#define REDO 2112   // REDO+0 = mean (per node), REDO+1 = rstd (per node)

typedef float f32x4 __attribute__((ext_vector_type(4)));

__device__ __forceinline__ float siluf(float x){ return x * (1.0f/(1.0f + __expf(-x))); }
__device__ __forceinline__ f32x4 silu4(f32x4 x){
  f32x4 r; r.x=siluf(x.x); r.y=siluf(x.y); r.z=siluf(x.z); r.w=siluf(x.w); return r;
}

struct W3Pack { float v[363]; };

// ------------------------- host: exact Wigner-3j (mirrors reference) -------------------------
static double factd(int n){ double f=1.0; for(int i=2;i<=n;++i) f*=(double)i; return f; }

static double su2_cg(int j1,int j2,int j3,int m1,int m2,int m3){
  if (m1+m2 != m3) return 0.0;
  double pref = std::sqrt((2.0*j3+1.0)*factd(j3+j1-j2)*factd(j3-j1+j2)*factd(j1+j2-j3)/factd(j1+j2+j3+1));
  pref *= std::sqrt(factd(j3+m3)*factd(j3-m3)*factd(j1-m1)*factd(j1+m1)*factd(j2-m2)*factd(j2+m2));
  double s=0.0;
  int vmin = std::max(0, std::max(j2-j3-m1, j1-j3+m2));
  int vmax = std::min(j2+m2, std::min(j1-m1, j1+j2-j3));
  for (int v=vmin; v<=vmax; ++v){
    double d = factd(v)*factd(j1+j2-j3-v)*factd(j1-m1-v)*factd(j2+m2-v)*factd(j3-j2+m1+v)*factd(j3-j1-m2+v);
    s += ((v&1)? -1.0 : 1.0)/d;
  }
  return pref*s;
}

typedef std::complex<double> cd;

static void qmat(int l, cd* q){
  int d=2*l+1;
  for (int a=0;a<d*d;++a) q[a]=cd(0,0);
  double is2 = 1.0/std::sqrt(2.0);
  for (int m=-l; m<0; ++m){
    int am=-m;
    q[(l+m)*d + (l+am)] = cd(is2,0);
    q[(l+m)*d + (l-am)] = cd(0,-is2);
  }
  q[l*d+l] = cd(1,0);
  for (int m=1;m<=l;++m){
    double sg = (m&1)? -1.0:1.0;
    q[(l+m)*d + (l+m)] = cd(sg*is2,0);
    q[(l+m)*d + (l-m)] = cd(0,sg*is2);
  }
  cd f = (l==0)? cd(1,0) : (l==1? cd(0,-1) : cd(-1,0)); // (-i)^l for l<=2
  for (int a=0;a<d*d;++a) q[a]*=f;
}

static void wigner3j(int l1,int l2,int l3, float* out){
  int d1=2*l1+1,d2=2*l2+1,d3=2*l3+1;
  double Cc[5][5][5] = {};
  for (int m1=-l1;m1<=l1;++m1) for (int m2=-l2;m2<=l2;++m2){
    int m3=m1+m2;
    if (m3>=-l3 && m3<=l3) Cc[l1+m1][l2+m2][l3+m3] = su2_cg(l1,l2,l3,m1,m2,m3);
  }
  cd q1[25],q2[25],q3[25];
  qmat(l1,q1); qmat(l2,q2); qmat(l3,q3);
  double re[125], im[125];
  double nr=0, ni=0;
  for (int i=0;i<d1;++i) for (int j=0;j<d2;++j) for (int k=0;k<d3;++k){
    cd s(0,0);
    for (int a=0;a<d1;++a) for (int b=0;b<d2;++b) for (int c=0;c<d3;++c){
      double cc = Cc[a][b][c];
      if (cc != 0.0) s += q1[a*d1+i]*q2[b*d2+j]*std::conj(q3[c*d3+k])*cc;
    }
    int o=(i*d2+j)*d3+k;
    re[o]=s.real(); im[o]=s.imag();
    nr += s.real()*s.real(); ni += s.imag()*s.imag();
  }
  bool useRe = std::sqrt(nr) >= std::sqrt(ni);
  double nrm = std::sqrt(useRe? nr : ni);
  for (int o=0;o<d1*d2*d3;++o) out[o] = (float)((useRe? re[o] : im[o]) / nrm);
}

static W3Pack build_w3(){
  W3Pack W;
  wigner3j(0,0,0, W.v+0);
  wigner3j(0,1,1, W.v+1);
  wigner3j(0,2,2, W.v+10);
  wigner3j(1,0,1, W.v+35);
  wigner3j(1,1,0, W.v+44);
  wigner3j(1,1,2, W.v+53);
  wigner3j(1,2,1, W.v+98);
  wigner3j(2,0,2, W.v+143);
  wigner3j(2,1,1, W.v+168);
  wigner3j(2,2,0, W.v+213);
  wigner3j(2,2,2, W.v+238);
  return W;
}

// ------------------------- device: tpw regroup (COLUMN-major = wave-coalesced, scale folded) -------------------------
// Group A (i2=0, M2=128, NJ=1): rows: p1 u(128) | p4 u(64) | p8 u(32)  -> wt[v*224 + r], v<128
// Group B (i2=1, M2=64,  NJ=3): rows: p2(128) | p5(64) | p6(64) | p9(32) -> wt[28672 + v*288 + r], v<64
// Group C (i2=2, M2=32,  NJ=5): rows: p3(128) | p7(64) | p10(32) | p11(32) -> wt[47104 + v*256 + r], v<32
__global__ __launch_bounds__(256) void prep_tpw(const float* __restrict__ tpw, float* __restrict__ wt)
{
  const int t = blockIdx.x*256 + threadIdx.x;
  if (t >= 55296) return;
  float v;
  if (t < 28672) {
    const int vv = t / 224, r = t - vv*224;
    int off, u;
    if (r < 128)      { off = 0;     u = r; }
    else if (r < 192) { off = 28672; u = r-128; }
    else              { off = 47104; u = r-192; }
    v = tpw[off + u*128 + vv] * 0.08838834764831845f;   // 1/sqrt(128)
  } else if (t < 47104) {
    const int t2 = t-28672; const int vv = t2/288, r = t2 - vv*288;
    int off, u;
    if (r < 128)      { off = 16384; u = r; }
    else if (r < 192) { off = 36864; u = r-128; }
    else if (r < 256) { off = 40960; u = r-192; }
    else              { off = 51200; u = r-256; }
    v = tpw[off + u*64 + vv] * 0.125f;                   // 1/sqrt(64)
  } else {
    const int t3 = t-47104; const int vv = t3/256, r = t3 & 255;
    int off, u;
    if (r < 128)      { off = 24576; u = r; }
    else if (r < 192) { off = 45056; u = r-128; }
    else if (r < 224) { off = 53248; u = r-192; }
    else              { off = 54272; u = r-224; }
    v = tpw[off + u*32 + vv] * 0.17677669529663687f;     // 1/sqrt(32)
  }
  wt[t] = v;
}

// ------------------------- column matvec: coalesced scalar weights, packed f32 over nodes -------------------------
// weights column-major (lane=col coalesced); x node-minor f32x4; acc4 += x4 * splat(w) -> v_pk_fma_f32
template<int N>
__device__ __forceinline__ f32x4 matcolP(const float* __restrict__ Wg, const int wstride, const int col,
                                         const f32x4* __restrict__ L4, const int inbase)
{
  f32x4 a0 = {}, a1 = {}, a2 = {}, a3 = {};
  const float* wp = Wg + col;
  #pragma unroll 2
  for (int u=0; u<N; u+=4) {
    const float wA = wp[(u+0)*wstride];
    const float wB = wp[(u+1)*wstride];
    const float wC = wp[(u+2)*wstride];
    const float wD = wp[(u+3)*wstride];
    a0 += L4[inbase+u+0]*wA;
    a1 += L4[inbase+u+1]*wB;
    a2 += L4[inbase+u+2]*wC;
    a3 += L4[inbase+u+3]*wD;
  }
  return (a0+a1)+(a2+a3);
}

// t-stage: NJ components share one coalesced weight column (stride wstride);
// JS = LDS element stride between components of the P block (64 for l=1, 32 for l=2)
template<int NJ, int M2, int JS>
__device__ __forceinline__ void tstageP(const float* __restrict__ wcol, const int wstride,
                                        const f32x4* __restrict__ L4, const int pbase,
                                        f32x4 (&t)[NJ])
{
  f32x4 acc[NJ];
  #pragma unroll
  for (int j=0;j<NJ;++j) acc[j] = (f32x4){};
  #pragma unroll 4
  for (int v=0; v<M2; ++v) {
    const float w = wcol[v*wstride];
    #pragma unroll
    for (int j=0;j<NJ;++j) acc[j] += L4[pbase + j*JS + v]*w;
  }
  #pragma unroll
  for (int j=0;j<NJ;++j) t[j] = acc[j];
}

// ------------------------- normgate (inv -> wave-parallel mean/var -> MLP -> G) -------------------------
__device__ __forceinline__ void normgate(f32x4* __restrict__ L4, const int c,
                                         const int B0, const int B1, const int B2,
                                         const float* __restrict__ gw1, const float* __restrict__ gb1,
                                         const float* __restrict__ gw2, const float* __restrict__ gb2)
{
  if (c < 128) {
    L4[INVO+c] = L4[B0+c];
  } else if (c < 192) {
    const int v = c-128;
    f32x4 s = {1e-12f,1e-12f,1e-12f,1e-12f};
    #pragma unroll
    for (int i=0;i<3;++i){ const f32x4 x = L4[B1+i*64+v]; s += x*x; }
    f32x4 r; r.x=sqrtf(s.x); r.y=sqrtf(s.y); r.z=sqrtf(s.z); r.w=sqrtf(s.w);
    L4[INVO+c] = r;
  } else if (c < 224) {
    const int v = c-192;
    f32x4 s = {1e-12f,1e-12f,1e-12f,1e-12f};
    #pragma unroll
    for (int i=0;i<5;++i){ const f32x4 x = L4[B2+i*32+v]; s += x*x; }
    f32x4 r; r.x=sqrtf(s.x); r.y=sqrtf(s.y); r.z=sqrtf(s.z); r.w=sqrtf(s.w);
    L4[INVO+c] = r;
  }
  __syncthreads();
  {
    const int w = c>>6, l = c&63;   // wave w <-> node w
    const float* Lf = (const float*)L4;
    float s=0.f, s2=0.f, x;
    x = Lf[(INVO+l)*4+w];     s+=x; s2+=x*x;
    x = Lf[(INVO+64+l)*4+w];  s+=x; s2+=x*x;
    x = Lf[(INVO+128+l)*4+w]; s+=x; s2+=x*x;
    if (l < 32) { x = Lf[(INVO+192+l)*4+w]; s+=x; s2+=x*x; }
    #pragma unroll
    for (int off=32; off>=1; off>>=1) {
      s  += __shfl_xor(s,  off, 64);
      s2 += __shfl_xor(s2, off, 64);
    }
    if (l==0) {
      float* Lw = (float*)L4;
      const float m = s*(1.f/224.f);
      Lw[REDO*4 + w]     = m;
      Lw[(REDO+1)*4 + w] = rsqrtf(s2*(1.f/224.f) - m*m + 1e-5f);
    }
  }
  __syncthreads();
  if (c < TMUL) {
    L4[INVO+c] = (L4[INVO+c]-L4[REDO])*L4[REDO+1];
  }
  __syncthreads();
  if (c < TMUL) {
    const f32x4 a = matcolP<224>(gw1, 224, c, L4, INVO);
    L4[HO+c] = silu4(a + gb1[c]);
  }
  __syncthreads();
  if (c < TMUL) {
    const f32x4 a = matcolP<224>(gw2, 224, c, L4, HO);
    L4[GO+c] = silu4(a + gb2[c]);
  }
  // no trailing sync: thread c's G[c] is self-written; callers sync before cross-thread G reads
}

// ------------------------- CG rows, groups B and C (t in regs, fused y, all f32x4) -------------------------
__device__ __forceinline__ void cg_rowB(const int r, const float* __restrict__ wt,
                                        const W3Pack& W, f32x4* __restrict__ L4)
{
  f32x4 tb[3];
  tstageP<3,64,64>(wt + 28672 + r, 288, L4, P1O, tb);   // LDS comp stride 64, weight stride 288
  if (r < 128) {                       // p2 (0,1,1): out C1 row r
    const f32x4 f = L4[F0O+r];
    #pragma unroll
    for (int k=0;k<3;++k) {
      f32x4 s = tb[0]*W.v[1+0*3+k] + tb[1]*W.v[1+1*3+k] + tb[2]*W.v[1+2*3+k];
      L4[C1O+k*288+r] = f*s;
    }
  } else if (r < 192) {                // p5 (1,1,0): out C0 row 128+u
    const int u=r-128;
    f32x4 y = {};
    #pragma unroll
    for (int i=0;i<3;++i) {
      f32x4 s = tb[0]*W.v[44+i*3+0] + tb[1]*W.v[44+i*3+1] + tb[2]*W.v[44+i*3+2];
      y += L4[F1O+i*64+u]*s;
    }
    L4[C0O+128+u] = y;
  } else if (r < 256) {                // p6 (1,1,2): out C2 row 128+u
    const int u=r-192;
    f32x4 f[3];
    #pragma unroll
    for (int i=0;i<3;++i) f[i]=L4[F1O+i*64+u];
    #pragma unroll
    for (int k=0;k<5;++k) {
      f32x4 y = {};
      #pragma unroll
      for (int i=0;i<3;++i) {
        f32x4 s = tb[0]*W.v[53+(i*3+0)*5+k] + tb[1]*W.v[53+(i*3+1)*5+k] + tb[2]*W.v[53+(i*3+2)*5+k];
        y += f[i]*s;
      }
      L4[C2O+k*256+128+u] = y;
    }
  } else {                             // p9 (2,1,1): out C1 row 256+u
    const int u=r-256;
    f32x4 f[5];
    #pragma unroll
    for (int i=0;i<5;++i) f[i]=L4[F2O+i*32+u];
    #pragma unroll
    for (int k=0;k<3;++k) {
      f32x4 y = {};
      #pragma unroll
      for (int i=0;i<5;++i) {
        f32x4 s = tb[0]*W.v[168+(i*3+0)*3+k] + tb[1]*W.v[168+(i*3+1)*3+k] + tb[2]*W.v[168+(i*3+2)*3+k];
        y += f[i]*s;
      }
      L4[C1O+k*288+256+u] = y;
    }
  }
}

__device__ __forceinline__ void cg_rowC(const int r, const float* __restrict__ wt,
                                        const W3Pack& W, f32x4* __restrict__ L4)
{
  f32x4 tc[5];
  tstageP<5,32,32>(wt + 47104 + r, 256, L4, P2O, tc);   // LDS comp stride 32, weight stride 256
  if (r < 128) {                       // p3 (0,2,2): out C2 row r
    const f32x4 f = L4[F0O+r];
    #pragma unroll
    for (int k=0;k<5;++k) {
      f32x4 s = {};
      #pragma unroll
      for (int j=0;j<5;++j) s += tc[j]*W.v[10+j*5+k];
      L4[C2O+k*256+r] = f*s;
    }
  } else if (r < 192) {                // p7 (1,2,1): out C1 row 192+u
    const int u=r-128;
    f32x4 f[3];
    #pragma unroll
    for (int i=0;i<3;++i) f[i]=L4[F1O+i*64+u];
    #pragma unroll
    for (int k=0;k<3;++k) {
      f32x4 y = {};
      #pragma unroll
      for (int i=0;i<3;++i) {
        f32x4 s = {};
        #pragma unroll
        for (int j=0;j<5;++j) s += tc[j]*W.v[98+(i*5+j)*3+k];
        y += f[i]*s;
      }
      L4[C1O+k*288+192+u] = y;
    }
  } else if (r < 224) {                // p10 (2,2,0): out C0 row 192+u
    const int u=r-192;
    f32x4 y = {};
    #pragma unroll
    for (int i=0;i<5;++i) {
      f32x4 s = {};
      #pragma unroll
      for (int j=0;j<5;++j) s += tc[j]*W.v[213+i*5+j];
      y += L4[F2O+i*32+u]*s;
    }
    L4[C0O+192+u] = y;
  } else {                             // p11 (2,2,2): out C2 row 224+u
    const int u=r-224;
    f32x4 f[5];
    #pragma unroll
    for (int i=0;i<5;++i) f[i]=L4[F2O+i*32+u];
    #pragma unroll
    for (int k=0;k<5;++k) {
      f32x4 y = {};
      #pragma unroll
      for (int i=0;i<5;++i) {
        f32x4 s = {};
        #pragma unroll
        for (int j=0;j<5;++j) s += tc[j]*W.v[238+(i*5+j)*5+k];
        y += f[i]*s;
      }
      L4[C2O+k*256+224+u] = y;
    }
  }
}

// ------------------------- fused kernel: NB nodes per block, node-minor LDS -------------------------
__global__ __launch_bounds__(256, 3) void fused4(
  const float* __restrict__ feat,
  const float* __restrict__ w0, const float* __restrict__ w1, const float* __restrict__ w2,
  const float* __restrict__ pgw1, const float* __restrict__ pgb1,
  const float* __restrict__ pgw2, const float* __restrict__ pgb2,
  const float* __restrict__ wt,
  const float* __restrict__ pw0, const float* __restrict__ pw1, const float* __restrict__ pw2,
  const float* __restrict__ qgw1, const float* __restrict__ qgb1,
  const float* __restrict__ qgw2, const float* __restrict__ qgb2,
  float* __restrict__ outp, const W3Pack W)
{
  __shared__ f32x4 L4[ST];
  float* Lf = (float*)L4;
  const int c = threadIdx.x;
  const size_t gbase = (size_t)blockIdx.x * (FEAT_DIM*NB);

  // ---- load + de-interleave (component-major elems, node-minor lanes) ----
  for (int t=c; t<FEAT_DIM*NB; t+=256) {
    const float val = feat[gbase + t];
    const int nb = t / FEAT_DIM;
    const int ch = t - nb*FEAT_DIM;
    int loc;
    if (ch < 128) loc = F0O + ch;
    else if (ch < 320) { const int q = ch-128; const int u = q/3; loc = F1O + (q-u*3)*64 + u; }
    else               { const int q = ch-320; const int u = q/5; loc = F2O + (q-u*5)*32 + u; }
    Lf[loc*4 + nb] = val;
  }
  __syncthreads();

  // ---- pre-linear (slot-balanced; coalesced original-layout weights) ----
  {
    f32x4 a1, a2 = {};
    int o1, o2=-1; float s1, s2s=0.f;
    if (c < 128) { a1 = matcolP<128>(w0, 128, c, L4, F0O); o1 = P0O+c; s1 = 0.08838834764831845f; }
    else { const int q=c-128; const int i=q>>6, v=q&63;
           a1 = matcolP<64>(w1, 64, v, L4, F1O+i*64); o1 = P1O+i*64+v; s1 = 0.125f; }
    if (c < 64) { a2 = matcolP<64>(w1, 64, c, L4, F1O+128); o2 = P1O+128+c; s2s = 0.125f; }
    else if (c < 224) { const int q=c-64; const int i=q>>5, v=q&31;
           a2 = matcolP<32>(w2, 32, v, L4, F2O+i*32); o2 = P2O+i*32+v; s2s = 0.17677669529663687f; }
    L4[o1] = a1*s1;
    if (o2 >= 0) L4[o2] = a2*s2s;
  }
  __syncthreads();

  // ---- pre normgate + gate P in place ----
  normgate(L4, c, P0O, P1O, P2O, pgw1, pgb1, pgw2, pgb2);
  if (c < 128) {
    L4[P0O+c] *= L4[GO+c];
  } else if (c < 192) {
    const int v=c-128; const f32x4 g=L4[GO+c];
    #pragma unroll
    for (int i=0;i<3;++i) L4[P1O+i*64+v] *= g;
  } else if (c < 224) {
    const int v=c-192; const f32x4 g=L4[GO+c];
    #pragma unroll
    for (int i=0;i<5;++i) L4[P2O+i*32+v] *= g;
  }
  __syncthreads();   // P gated; also guarantees all MLP2 H-reads done before CG overwrites scratch

  // ---- CG coupling: group A (thread=row, t in reg, 2 acc chains) ----
  if (c < 224) {
    f32x4 ta0 = {}, ta1 = {};
    const float* wp = wt + c;          // stride 224, coalesced
    #pragma unroll 2
    for (int v=0; v<128; v+=2) {
      const float wA = wp[v*224], wB = wp[(v+1)*224];
      ta0 += L4[P0O+v]*wA;
      ta1 += L4[P0O+v+1]*wB;
    }
    const f32x4 tA = ta0 + ta1;
    if (c < 128) {                     // p1 (0,0,0): out C0 row c
      L4[C0O+c] = L4[F0O+c]*tA*W.v[0];
    } else if (c < 192) {              // p4 (1,0,1): out C1 row 128+u
      const int u=c-128;
      const f32x4 f0=L4[F1O+u], f1=L4[F1O+64+u], f2=L4[F1O+128+u];
      #pragma unroll
      for (int k=0;k<3;++k)
        L4[C1O+k*288+128+u] = tA*(f0*W.v[35+k] + f1*W.v[38+k] + f2*W.v[41+k]);
    } else {                           // p8 (2,0,2): out C2 row 192+u
      const int u=c-192;
      f32x4 f[5];
      #pragma unroll
      for (int i=0;i<5;++i) f[i]=L4[F2O+i*32+u];
      #pragma unroll
      for (int k=0;k<5;++k) {
        f32x4 y = {};
        #pragma unroll
        for (int i=0;i<5;++i) y += f[i]*W.v[143+i*5+k];
        L4[C2O+k*256+192+u] = tA*y;
      }
    }
  }
  // groups B (288 rows) and C (256 rows)
  cg_rowB(c, wt, W, L4);
  if (c >= 224) cg_rowB(c+32, wt, W, L4);
  cg_rowC(c, wt, W, L4);
  __syncthreads();

  // ---- post-linear (reg-staged: Q overlays C head, write after all C reads) ----
  {
    f32x4 pa, pb = {};
    int po1, po2=-1; float ps1, ps2=0.f;
    if (c < 128) { pa = matcolP<224>(pw0, 128, c, L4, C0O); po1 = Q0O+c; ps1 = 0.06681531047810609f; }
    else { const int q=c-128; const int i=q>>6, v=q&63;
           pa = matcolP<288>(pw1, 64, v, L4, C1O+i*288); po1 = Q1O+i*64+v; ps1 = 0.05892556509887896f; }
    if (c < 64) { pb = matcolP<288>(pw1, 64, c, L4, C1O+2*288); po2 = Q1O+128+c; ps2 = 0.05892556509887896f; }
    else if (c < 224) { const int q=c-64; const int i=q>>5, v=q&31;
           pb = matcolP<256>(pw2, 32, v, L4, C2O+i*256); po2 = Q2O+i*32+v; ps2 = 0.0625f; }
    __syncthreads();   // all C reads complete before Q overwrite
    L4[po1] = pa*ps1;
    if (po2 >= 0) L4[po2] = pb*ps2;
  }
  __syncthreads();

  // ---- post normgate ----
  normgate(L4, c, Q0O, Q1O, Q2O, qgw1, qgb1, qgw2, qgb2);
  __syncthreads();   // final reads G cross-thread

  // ---- final: out = feat + pre_gated + post*G (re-interleave, coalesced store) ----
  for (int t=c; t<FEAT_DIM*NB; t+=256) {
    const int nb = t / FEAT_DIM;
    const int ch = t - nb*FEAT_DIM;
    float val;
    if (ch < 128) {
      val = Lf[(F0O+ch)*4+nb] + Lf[(P0O+ch)*4+nb] + Lf[(Q0O+ch)*4+nb]*Lf[(GO+ch)*4+nb];
    } else if (ch < 320) {
      const int q=ch-128; const int u=q/3; const int o=(q-u*3)*64+u;
      val = Lf[(F1O+o)*4+nb] + Lf[(P1O+o)*4+nb] + Lf[(Q1O+o)*4+nb]*Lf[(GO+128+u)*4+nb];
    } else {
      const int q=ch-320; const int u=q/5; const int o=(q-u*5)*32+u;
      val = Lf[(F2O+o)*4+nb] + Lf[(P2O+o)*4+nb] + Lf[(Q2O+o)*4+nb]*Lf[(GO+192+u)*4+nb];
    }
    outp[gbase + t] = val;
  }
}

// ------------------------- launch -------------------------
extern "C" void kernel_launch(void* const* d_in, const int* in_sizes, int n_in,
                              void* d_out, int out_size, void* d_ws, size_t ws_size,
                              hipStream_t stream)
{
  (void)in_sizes; (void)n_in; (void)out_size; (void)ws_size;
  const float* feat  = (const float*)d_in[0];
  const float* prw0  = (const float*)d_in[1];
  const float* prw1  = (const float*)d_in[2];
  const float* prw2  = (const float*)d_in[3];
  const float* pngw1 = (const float*)d_in[4];
  const float* pngb1 = (const float*)d_in[5];
  const float* pngw2 = (const float*)d_in[6];
  const float* pngb2 = (const float*)d_in[7];
  const float* tpw   = (const float*)d_in[8];
  const float* pow0  = (const float*)d_in[9];
  const float* pow1  = (const float*)d_in[10];
  const float* pow2  = (const float*)d_in[11];
  const float* qngw1 = (const float*)d_in[12];
  const float* qngb1 = (const float*)d_in[13];
  const float* qngw2 = (const float*)d_in[14];
  const float* qngb2 = (const float*)d_in[15];

  float* wt = (float*)d_ws;            // 55296 floats: regrouped tpw (column-major, coalesced)

  W3Pack W = build_w3();               // host-only, identical every call

  prep_tpw<<<dim3(216), dim3(256), 0, stream>>>(tpw, wt);

  fused4<<<dim3(N_NODES/NB), dim3(256), 0, stream>>>(
      feat, prw0, prw1, prw2, pngw1, pngb1, pngw2, pngb2,
      wt, pow0, pow1, pow2, qngw1, qngb1, qngw2, qngb2,
      (float*)d_out, W);
}

// Round 6
// 1075.115 us; speedup vs baseline: 1.6311x; 1.1647x over previous
//
#include <hip/hip_runtime.h>
#include <cmath>
#include <complex>
#include <algorithm>

#define N_NODES  32768
#define FEAT_DIM 480
#define TMUL     224
#define NB       4
#define ST       3328   // element count; LDS = ST elems, each elem = 4 nodes x bf16 = 8B (2 uints)

// element offsets (same map as f32 version)
#define F0O 0
#define F1O 128
#define F2O 320
#define P0O 480
#define P1O 608
#define P2O 800
#define C0O 960
#define C1O 1184
#define C2O 2048
#define Q0O 960
#define Q1O 1088
#define Q2O 1280
#define INVO 1440
#define HO   1664
#define GO   1888

typedef float f32x4 __attribute__((ext_vector_type(4)));

__device__ __forceinline__ float siluf(float x){ return x * (1.0f/(1.0f + __expf(-x))); }
__device__ __forceinline__ f32x4 silu4(f32x4 x){
  f32x4 r; r.x=siluf(x.x); r.y=siluf(x.y); r.z=siluf(x.z); r.w=siluf(x.w); return r;
}
__device__ __forceinline__ f32x4 sqrt4(f32x4 x){
  f32x4 r; r.x=sqrtf(x.x); r.y=sqrtf(x.y); r.z=sqrtf(x.z); r.w=sqrtf(x.w); return r;
}

// ---- bf16 pack/unpack (RNE; finite values only) ----
__device__ __forceinline__ float bfh(ushort h){ return __uint_as_float(((uint)h)<<16); }
__device__ __forceinline__ ushort f2bf(float f){
  uint u=__float_as_uint(f); return (ushort)((u + 0x7fffu + ((u>>16)&1u))>>16);
}
__device__ __forceinline__ f32x4 X0q(uint4 q){
  f32x4 r = {__uint_as_float(q.x<<16), __uint_as_float(q.x&0xffff0000u),
             __uint_as_float(q.y<<16), __uint_as_float(q.y&0xffff0000u)};
  return r;
}
__device__ __forceinline__ f32x4 X1q(uint4 q){
  f32x4 r = {__uint_as_float(q.z<<16), __uint_as_float(q.z&0xffff0000u),
             __uint_as_float(q.w<<16), __uint_as_float(q.w&0xffff0000u)};
  return r;
}
__device__ __forceinline__ f32x4 ldE(const uint* __restrict__ Lb, int e){
  uint2 q = *(const uint2*)&Lb[e*2];
  f32x4 r = {__uint_as_float(q.x<<16), __uint_as_float(q.x&0xffff0000u),
             __uint_as_float(q.y<<16), __uint_as_float(q.y&0xffff0000u)};
  return r;
}
__device__ __forceinline__ void stE(uint* __restrict__ Lb, int e, f32x4 x){
  uint2 q = { (uint)f2bf(x.x) | ((uint)f2bf(x.y)<<16),
              (uint)f2bf(x.z) | ((uint)f2bf(x.w)<<16) };
  *(uint2*)&Lb[e*2] = q;
}

struct W3Pack { float v[363]; };

// ------------------------- host: exact Wigner-3j (mirrors reference) -------------------------
static double factd(int n){ double f=1.0; for(int i=2;i<=n;++i) f*=(double)i; return f; }

static double su2_cg(int j1,int j2,int j3,int m1,int m2,int m3){
  if (m1+m2 != m3) return 0.0;
  double pref = std::sqrt((2.0*j3+1.0)*factd(j3+j1-j2)*factd(j3-j1+j2)*factd(j1+j2-j3)/factd(j1+j2+j3+1));
  pref *= std::sqrt(factd(j3+m3)*factd(j3-m3)*factd(j1-m1)*factd(j1+m1)*factd(j2-m2)*factd(j2+m2));
  double s=0.0;
  int vmin = std::max(0, std::max(j2-j3-m1, j1-j3+m2));
  int vmax = std::min(j2+m2, std::min(j1-m1, j1+j2-j3));
  for (int v=vmin; v<=vmax; ++v){
    double d = factd(v)*factd(j1+j2-j3-v)*factd(j1-m1-v)*factd(j2+m2-v)*factd(j3-j2+m1+v)*factd(j3-j1-m2+v);
    s += ((v&1)? -1.0 : 1.0)/d;
  }
  return pref*s;
}

typedef std::complex<double> cd;

static void qmat(int l, cd* q){
  int d=2*l+1;
  for (int a=0;a<d*d;++a) q[a]=cd(0,0);
  double is2 = 1.0/std::sqrt(2.0);
  for (int m=-l; m<0; ++m){
    int am=-m;
    q[(l+m)*d + (l+am)] = cd(is2,0);
    q[(l+m)*d + (l-am)] = cd(0,-is2);
  }
  q[l*d+l] = cd(1,0);
  for (int m=1;m<=l;++m){
    double sg = (m&1)? -1.0:1.0;
    q[(l+m)*d + (l+m)] = cd(sg*is2,0);
    q[(l+m)*d + (l-m)] = cd(0,sg*is2);
  }
  cd f = (l==0)? cd(1,0) : (l==1? cd(0,-1) : cd(-1,0)); // (-i)^l for l<=2
  for (int a=0;a<d*d;++a) q[a]*=f;
}

static void wigner3j(int l1,int l2,int l3, float* out){
  int d1=2*l1+1,d2=2*l2+1,d3=2*l3+1;
  double Cc[5][5][5] = {};
  for (int m1=-l1;m1<=l1;++m1) for (int m2=-l2;m2<=l2;++m2){
    int m3=m1+m2;
    if (m3>=-l3 && m3<=l3) Cc[l1+m1][l2+m2][l3+m3] = su2_cg(l1,l2,l3,m1,m2,m3);
  }
  cd q1[25],q2[25],q3[25];
  qmat(l1,q1); qmat(l2,q2); qmat(l3,q3);
  double re[125], im[125];
  double nr=0, ni=0;
  for (int i=0;i<d1;++i) for (int j=0;j<d2;++j) for (int k=0;k<d3;++k){
    cd s(0,0);
    for (int a=0;a<d1;++a) for (int b=0;b<d2;++b) for (int c=0;c<d3;++c){
      double cc = Cc[a][b][c];
      if (cc != 0.0) s += q1[a*d1+i]*q2[b*d2+j]*std::conj(q3[c*d3+k])*cc;
    }
    int o=(i*d2+j)*d3+k;
    re[o]=s.real(); im[o]=s.imag();
    nr += s.real()*s.real(); ni += s.imag()*s.imag();
  }
  bool useRe = std::sqrt(nr) >= std::sqrt(ni);
  double nrm = std::sqrt(useRe? nr : ni);
  for (int o=0;o<d1*d2*d3;++o) out[o] = (float)((useRe? re[o] : im[o]) / nrm);
}

static W3Pack build_w3(){
  W3Pack W;
  wigner3j(0,0,0, W.v+0);
  wigner3j(0,1,1, W.v+1);
  wigner3j(0,2,2, W.v+10);
  wigner3j(1,0,1, W.v+35);
  wigner3j(1,1,0, W.v+44);
  wigner3j(1,1,2, W.v+53);
  wigner3j(1,2,1, W.v+98);
  wigner3j(2,0,2, W.v+143);
  wigner3j(2,1,1, W.v+168);
  wigner3j(2,2,0, W.v+213);
  wigner3j(2,2,2, W.v+238);
  return W;
}

// ------------------------- device: tpw regroup (COLUMN-major = wave-coalesced, scale folded) -------------------------
__global__ __launch_bounds__(256) void prep_tpw(const float* __restrict__ tpw, float* __restrict__ wt)
{
  const int t = blockIdx.x*256 + threadIdx.x;
  if (t >= 55296) return;
  float v;
  if (t < 28672) {
    const int vv = t / 224, r = t - vv*224;
    int off, u;
    if (r < 128)      { off = 0;     u = r; }
    else if (r < 192) { off = 28672; u = r-128; }
    else              { off = 47104; u = r-192; }
    v = tpw[off + u*128 + vv] * 0.08838834764831845f;   // 1/sqrt(128)
  } else if (t < 47104) {
    const int t2 = t-28672; const int vv = t2/288, r = t2 - vv*288;
    int off, u;
    if (r < 128)      { off = 16384; u = r; }
    else if (r < 192) { off = 36864; u = r-128; }
    else if (r < 256) { off = 40960; u = r-192; }
    else              { off = 51200; u = r-256; }
    v = tpw[off + u*64 + vv] * 0.125f;                   // 1/sqrt(64)
  } else {
    const int t3 = t-47104; const int vv = t3/256, r = t3 & 255;
    int off, u;
    if (r < 128)      { off = 24576; u = r; }
    else if (r < 192) { off = 45056; u = r-128; }
    else if (r < 224) { off = 53248; u = r-192; }
    else              { off = 54272; u = r-224; }
    v = tpw[off + u*32 + vv] * 0.17677669529663687f;     // 1/sqrt(32)
  }
  wt[t] = v;
}

// ------------------------- bf16-LDS column matvec: 1 ds_read_b128 = 2 elems x 4 nodes -------------------------
template<int N>
__device__ __forceinline__ f32x4 matcolB(const float* __restrict__ Wg, const int wstride, const int col,
                                         const uint* __restrict__ Lb, const int inbase)
{
  f32x4 a0={}, a1={}, a2={}, a3={};
  const float* wp = Wg + col;
  #pragma unroll 2
  for (int u=0; u<N; u+=4) {
    const float wA = wp[(u+0)*wstride];
    const float wB = wp[(u+1)*wstride];
    const float wC = wp[(u+2)*wstride];
    const float wD = wp[(u+3)*wstride];
    const uint4 qa = *(const uint4*)&Lb[(inbase+u)*2];
    const uint4 qb = *(const uint4*)&Lb[(inbase+u+2)*2];
    a0 += X0q(qa)*wA;
    a1 += X1q(qa)*wB;
    a2 += X0q(qb)*wC;
    a3 += X1q(qb)*wD;
  }
  return (a0+a1)+(a2+a3);
}

// t-stage: NJ components share one coalesced weight column; JS = LDS elem stride between components
template<int NJ, int M2, int JS>
__device__ __forceinline__ void tstageB(const float* __restrict__ wcol, const int wstride,
                                        const uint* __restrict__ Lb, const int pbase,
                                        f32x4 (&t)[NJ])
{
  f32x4 a0[NJ], a1[NJ];
  #pragma unroll
  for (int j=0;j<NJ;++j){ a0[j]=(f32x4){}; a1[j]=(f32x4){}; }
  #pragma unroll 2
  for (int v=0; v<M2; v+=2) {
    const float wA = wcol[v*wstride];
    const float wB = wcol[(v+1)*wstride];
    #pragma unroll
    for (int j=0;j<NJ;++j) {
      const uint4 q = *(const uint4*)&Lb[(pbase + j*JS + v)*2];
      a0[j] += X0q(q)*wA;
      a1[j] += X1q(q)*wB;
    }
  }
  #pragma unroll
  for (int j=0;j<NJ;++j) t[j] = a0[j]+a1[j];
}

// ------------------------- normgate (bf16 LDS; mean/rstd in f32 side-array) -------------------------
__device__ __forceinline__ void normgateB(uint* __restrict__ Lb, ushort* __restrict__ Lb16,
                                          f32x4* __restrict__ sRed, const int c,
                                          const int B0, const int B1, const int B2,
                                          const float* __restrict__ gw1, const float* __restrict__ gb1,
                                          const float* __restrict__ gw2, const float* __restrict__ gb2)
{
  if (c < 128) {
    const uint2 q = *(const uint2*)&Lb[(B0+c)*2];       // bf16->bf16 copy, lossless
    *(uint2*)&Lb[(INVO+c)*2] = q;
  } else if (c < 192) {
    const int v = c-128;
    f32x4 s = {1e-12f,1e-12f,1e-12f,1e-12f};
    #pragma unroll
    for (int i=0;i<3;++i){ const f32x4 x = ldE(Lb, B1+i*64+v); s += x*x; }
    stE(Lb, INVO+c, sqrt4(s));
  } else if (c < 224) {
    const int v = c-192;
    f32x4 s = {1e-12f,1e-12f,1e-12f,1e-12f};
    #pragma unroll
    for (int i=0;i<5;++i){ const f32x4 x = ldE(Lb, B2+i*32+v); s += x*x; }
    stE(Lb, INVO+c, sqrt4(s));
  }
  __syncthreads();
  {
    const int w = c>>6, l = c&63;   // wave w <-> node w
    float s=0.f, s2=0.f, x;
    x = bfh(Lb16[(INVO+l)*4+w]);      s+=x; s2+=x*x;
    x = bfh(Lb16[(INVO+64+l)*4+w]);   s+=x; s2+=x*x;
    x = bfh(Lb16[(INVO+128+l)*4+w]);  s+=x; s2+=x*x;
    if (l < 32) { x = bfh(Lb16[(INVO+192+l)*4+w]); s+=x; s2+=x*x; }
    #pragma unroll
    for (int off=32; off>=1; off>>=1) {
      s  += __shfl_xor(s,  off, 64);
      s2 += __shfl_xor(s2, off, 64);
    }
    if (l==0) {
      const float m = s*(1.f/224.f);
      ((float*)&sRed[0])[w] = m;
      ((float*)&sRed[1])[w] = rsqrtf(s2*(1.f/224.f) - m*m + 1e-5f);
    }
  }
  __syncthreads();
  if (c < TMUL) {
    const f32x4 x = ldE(Lb, INVO+c);
    stE(Lb, INVO+c, (x - sRed[0])*sRed[1]);
  }
  __syncthreads();
  if (c < TMUL) {
    const f32x4 a = matcolB<224>(gw1, 224, c, Lb, INVO);
    stE(Lb, HO+c, silu4(a + gb1[c]));
  }
  __syncthreads();
  if (c < TMUL) {
    const f32x4 a = matcolB<224>(gw2, 224, c, Lb, HO);
    stE(Lb, GO+c, silu4(a + gb2[c]));
  }
  // no trailing sync: thread c's G[c] is self-written; callers sync before cross-thread G reads
}

// ------------------------- CG rows, groups B and C -------------------------
__device__ __forceinline__ void cg_rowB(const int r, const float* __restrict__ wt,
                                        const W3Pack& W, uint* __restrict__ Lb)
{
  f32x4 tb[3];
  tstageB<3,64,64>(wt + 28672 + r, 288, Lb, P1O, tb);
  if (r < 128) {                       // p2 (0,1,1): out C1 row r
    const f32x4 f = ldE(Lb, F0O+r);
    #pragma unroll
    for (int k=0;k<3;++k) {
      f32x4 s = tb[0]*W.v[1+0*3+k] + tb[1]*W.v[1+1*3+k] + tb[2]*W.v[1+2*3+k];
      stE(Lb, C1O+k*288+r, f*s);
    }
  } else if (r < 192) {                // p5 (1,1,0): out C0 row 128+u
    const int u=r-128;
    f32x4 y = {};
    #pragma unroll
    for (int i=0;i<3;++i) {
      f32x4 s = tb[0]*W.v[44+i*3+0] + tb[1]*W.v[44+i*3+1] + tb[2]*W.v[44+i*3+2];
      y += ldE(Lb, F1O+i*64+u)*s;
    }
    stE(Lb, C0O+128+u, y);
  } else if (r < 256) {                // p6 (1,1,2): out C2 row 128+u
    const int u=r-192;
    f32x4 f[3];
    #pragma unroll
    for (int i=0;i<3;++i) f[i]=ldE(Lb, F1O+i*64+u);
    #pragma unroll
    for (int k=0;k<5;++k) {
      f32x4 y = {};
      #pragma unroll
      for (int i=0;i<3;++i) {
        f32x4 s = tb[0]*W.v[53+(i*3+0)*5+k] + tb[1]*W.v[53+(i*3+1)*5+k] + tb[2]*W.v[53+(i*3+2)*5+k];
        y += f[i]*s;
      }
      stE(Lb, C2O+k*256+128+u, y);
    }
  } else {                             // p9 (2,1,1): out C1 row 256+u
    const int u=r-256;
    f32x4 f[5];
    #pragma unroll
    for (int i=0;i<5;++i) f[i]=ldE(Lb, F2O+i*32+u);
    #pragma unroll
    for (int k=0;k<3;++k) {
      f32x4 y = {};
      #pragma unroll
      for (int i=0;i<5;++i) {
        f32x4 s = tb[0]*W.v[168+(i*3+0)*3+k] + tb[1]*W.v[168+(i*3+1)*3+k] + tb[2]*W.v[168+(i*3+2)*3+k];
        y += f[i]*s;
      }
      stE(Lb, C1O+k*288+256+u, y);
    }
  }
}

__device__ __forceinline__ void cg_rowC(const int r, const float* __restrict__ wt,
                                        const W3Pack& W, uint* __restrict__ Lb)
{
  f32x4 tc[5];
  tstageB<5,32,32>(wt + 47104 + r, 256, Lb, P2O, tc);
  if (r < 128) {                       // p3 (0,2,2): out C2 row r
    const f32x4 f = ldE(Lb, F0O+r);
    #pragma unroll
    for (int k=0;k<5;++k) {
      f32x4 s = {};
      #pragma unroll
      for (int j=0;j<5;++j) s += tc[j]*W.v[10+j*5+k];
      stE(Lb, C2O+k*256+r, f*s);
    }
  } else if (r < 192) {                // p7 (1,2,1): out C1 row 192+u
    const int u=r-128;
    f32x4 f[3];
    #pragma unroll
    for (int i=0;i<3;++i) f[i]=ldE(Lb, F1O+i*64+u);
    #pragma unroll
    for (int k=0;k<3;++k) {
      f32x4 y = {};
      #pragma unroll
      for (int i=0;i<3;++i) {
        f32x4 s = {};
        #pragma unroll
        for (int j=0;j<5;++j) s += tc[j]*W.v[98+(i*5+j)*3+k];
        y += f[i]*s;
      }
      stE(Lb, C1O+k*288+192+u, y);
    }
  } else if (r < 224) {                // p10 (2,2,0): out C0 row 192+u
    const int u=r-192;
    f32x4 y = {};
    #pragma unroll
    for (int i=0;i<5;++i) {
      f32x4 s = {};
      #pragma unroll
      for (int j=0;j<5;++j) s += tc[j]*W.v[213+i*5+j];
      y += ldE(Lb, F2O+i*32+u)*s;
    }
    stE(Lb, C0O+192+u, y);
  } else {                             // p11 (2,2,2): out C2 row 224+u
    const int u=r-224;
    f32x4 f[5];
    #pragma unroll
    for (int i=0;i<5;++i) f[i]=ldE(Lb, F2O+i*32+u);
    #pragma unroll
    for (int k=0;k<5;++k) {
      f32x4 y = {};
      #pragma unroll
      for (int i=0;i<5;++i) {
        f32x4 s = {};
        #pragma unroll
        for (int j=0;j<5;++j) s += tc[j]*W.v[238+(i*5+j)*5+k];
        y += f[i]*s;
      }
      stE(Lb, C2O+k*256+224+u, y);
    }
  }
}

// ------------------------- fused kernel: NB nodes per block, bf16 node-minor LDS -------------------------
__global__ __launch_bounds__(256, 4) void fused4(
  const float* __restrict__ feat,
  const float* __restrict__ w0, const float* __restrict__ w1, const float* __restrict__ w2,
  const float* __restrict__ pgw1, const float* __restrict__ pgb1,
  const float* __restrict__ pgw2, const float* __restrict__ pgb2,
  const float* __restrict__ wt,
  const float* __restrict__ pw0, const float* __restrict__ pw1, const float* __restrict__ pw2,
  const float* __restrict__ qgw1, const float* __restrict__ qgb1,
  const float* __restrict__ qgw2, const float* __restrict__ qgb2,
  float* __restrict__ outp, const W3Pack W)
{
  __shared__ uint LbU[ST*2];          // 26624 B
  __shared__ f32x4 sRed[2];           // mean, rstd (f32, per node)
  uint* Lb = LbU;
  ushort* Lb16 = (ushort*)LbU;
  const int c = threadIdx.x;
  const size_t gbase = (size_t)blockIdx.x * (FEAT_DIM*NB);

  // ---- load + de-interleave (component-major elems, node-minor bf16) ----
  for (int t=c; t<FEAT_DIM*NB; t+=256) {
    const float val = feat[gbase + t];
    const int nb = t / FEAT_DIM;
    const int ch = t - nb*FEAT_DIM;
    int loc;
    if (ch < 128) loc = F0O + ch;
    else if (ch < 320) { const int q = ch-128; const int u = q/3; loc = F1O + (q-u*3)*64 + u; }
    else               { const int q = ch-320; const int u = q/5; loc = F2O + (q-u*5)*32 + u; }
    Lb16[loc*4 + nb] = f2bf(val);
  }
  __syncthreads();

  // ---- pre-linear (slot-balanced; coalesced original-layout weights) ----
  {
    f32x4 a1, a2 = {};
    int o1, o2=-1; float s1, s2s=0.f;
    if (c < 128) { a1 = matcolB<128>(w0, 128, c, Lb, F0O); o1 = P0O+c; s1 = 0.08838834764831845f; }
    else { const int q=c-128; const int i=q>>6, v=q&63;
           a1 = matcolB<64>(w1, 64, v, Lb, F1O+i*64); o1 = P1O+i*64+v; s1 = 0.125f; }
    if (c < 64) { a2 = matcolB<64>(w1, 64, c, Lb, F1O+128); o2 = P1O+128+c; s2s = 0.125f; }
    else if (c < 224) { const int q=c-64; const int i=q>>5, v=q&31;
           a2 = matcolB<32>(w2, 32, v, Lb, F2O+i*32); o2 = P2O+i*32+v; s2s = 0.17677669529663687f; }
    stE(Lb, o1, a1*s1);
    if (o2 >= 0) stE(Lb, o2, a2*s2s);
  }
  __syncthreads();

  // ---- pre normgate + gate P in place ----
  normgateB(Lb, Lb16, sRed, c, P0O, P1O, P2O, pgw1, pgb1, pgw2, pgb2);
  if (c < 128) {
    stE(Lb, P0O+c, ldE(Lb,P0O+c)*ldE(Lb,GO+c));
  } else if (c < 192) {
    const int v=c-128; const f32x4 g=ldE(Lb,GO+c);
    #pragma unroll
    for (int i=0;i<3;++i) stE(Lb, P1O+i*64+v, ldE(Lb,P1O+i*64+v)*g);
  } else if (c < 224) {
    const int v=c-192; const f32x4 g=ldE(Lb,GO+c);
    #pragma unroll
    for (int i=0;i<5;++i) stE(Lb, P2O+i*32+v, ldE(Lb,P2O+i*32+v)*g);
  }
  __syncthreads();   // P gated; also guarantees all MLP2 H-reads done before CG overwrites scratch

  // ---- CG coupling: group A (thread=row; t = matcolB over P0) ----
  if (c < 224) {
    const f32x4 tA = matcolB<128>(wt, 224, c, Lb, P0O);
    if (c < 128) {                     // p1 (0,0,0): out C0 row c
      stE(Lb, C0O+c, ldE(Lb,F0O+c)*tA*W.v[0]);
    } else if (c < 192) {              // p4 (1,0,1): out C1 row 128+u
      const int u=c-128;
      const f32x4 f0=ldE(Lb,F1O+u), f1=ldE(Lb,F1O+64+u), f2=ldE(Lb,F1O+128+u);
      #pragma unroll
      for (int k=0;k<3;++k)
        stE(Lb, C1O+k*288+128+u, tA*(f0*W.v[35+k] + f1*W.v[38+k] + f2*W.v[41+k]));
    } else {                           // p8 (2,0,2): out C2 row 192+u
      const int u=c-192;
      f32x4 f[5];
      #pragma unroll
      for (int i=0;i<5;++i) f[i]=ldE(Lb,F2O+i*32+u);
      #pragma unroll
      for (int k=0;k<5;++k) {
        f32x4 y = {};
        #pragma unroll
        for (int i=0;i<5;++i) y += f[i]*W.v[143+i*5+k];
        stE(Lb, C2O+k*256+192+u, tA*y);
      }
    }
  }
  // groups B (288 rows) and C (256 rows)
  cg_rowB(c, wt, W, Lb);
  if (c >= 224) cg_rowB(c+32, wt, W, Lb);
  cg_rowC(c, wt, W, Lb);
  __syncthreads();

  // ---- post-linear (reg-staged: Q overlays C head, write after all C reads) ----
  {
    f32x4 pa, pb = {};
    int po1, po2=-1; float ps1, ps2=0.f;
    if (c < 128) { pa = matcolB<224>(pw0, 128, c, Lb, C0O); po1 = Q0O+c; ps1 = 0.06681531047810609f; }
    else { const int q=c-128; const int i=q>>6, v=q&63;
           pa = matcolB<288>(pw1, 64, v, Lb, C1O+i*288); po1 = Q1O+i*64+v; ps1 = 0.05892556509887896f; }
    if (c < 64) { pb = matcolB<288>(pw1, 64, c, Lb, C1O+2*288); po2 = Q1O+128+c; ps2 = 0.05892556509887896f; }
    else if (c < 224) { const int q=c-64; const int i=q>>5, v=q&31;
           pb = matcolB<256>(pw2, 32, v, Lb, C2O+i*256); po2 = Q2O+i*32+v; ps2 = 0.0625f; }
    __syncthreads();   // all C reads complete before Q overwrite
    stE(Lb, po1, pa*ps1);
    if (po2 >= 0) stE(Lb, po2, pb*ps2);
  }
  __syncthreads();

  // ---- post normgate ----
  normgateB(Lb, Lb16, sRed, c, Q0O, Q1O, Q2O, qgw1, qgb1, qgw2, qgb2);
  __syncthreads();   // final reads G cross-thread

  // ---- final: out = feat(f32, re-read) + pre_gated + post*G (coalesced) ----
  for (int t=c; t<FEAT_DIM*NB; t+=256) {
    const int nb = t / FEAT_DIM;
    const int ch = t - nb*FEAT_DIM;
    float pre, q, g;
    if (ch < 128) {
      pre = bfh(Lb16[(P0O+ch)*4+nb]);
      q   = bfh(Lb16[(Q0O+ch)*4+nb]);
      g   = bfh(Lb16[(GO+ch)*4+nb]);
    } else if (ch < 320) {
      const int qq=ch-128; const int u=qq/3; const int o=(qq-u*3)*64+u;
      pre = bfh(Lb16[(P1O+o)*4+nb]);
      q   = bfh(Lb16[(Q1O+o)*4+nb]);
      g   = bfh(Lb16[(GO+128+u)*4+nb]);
    } else {
      const int qq=ch-320; const int u=qq/5; const int o=(qq-u*5)*32+u;
      pre = bfh(Lb16[(P2O+o)*4+nb]);
      q   = bfh(Lb16[(Q2O+o)*4+nb]);
      g   = bfh(Lb16[(GO+192+u)*4+nb]);
    }
    outp[gbase + t] = feat[gbase + t] + pre + q*g;
  }
}

// ------------------------- launch -------------------------
extern "C" void kernel_launch(void* const* d_in, const int* in_sizes, int n_in,
                              void* d_out, int out_size, void* d_ws, size_t ws_size,
                              hipStream_t stream)
{
  (void)in_sizes; (void)n_in; (void)out_size; (void)ws_size;
  const float* feat  = (const float*)d_in[0];
  const float* prw0  = (const float*)d_in[1];
  const float* prw1  = (const float*)d_in[2];
  const float* prw2  = (const float*)d_in[3];
  const float* pngw1 = (const float*)d_in[4];
  const float* pngb1 = (const float*)d_in[5];
  const float* pngw2 = (const float*)d_in[6];
  const float* pngb2 = (const float*)d_in[7];
  const float* tpw   = (const float*)d_in[8];
  const float* pow0  = (const float*)d_in[9];
  const float* pow1  = (const float*)d_in[10];
  const float* pow2  = (const float*)d_in[11];
  const float* qngw1 = (const float*)d_in[12];
  const float* qngb1 = (const float*)d_in[13];
  const float* qngw2 = (const float*)d_in[14];
  const float* qngb2 = (const float*)d_in[15];

  float* wt = (float*)d_ws;            // 55296 floats: regrouped tpw (column-major, coalesced)

  W3Pack W = build_w3();               // host-only, identical every call

  prep_tpw<<<dim3(216), dim3(256), 0, stream>>>(tpw, wt);

  fused4<<<dim3(N_NODES/NB), dim3(256), 0, stream>>>(
      feat, prw0, prw1, prw2, pngw1, pngb1, pngw2, pngb2,
      wt, pow0, pow1, pow2, qngw1, qngb1, qngw2, qngb2,
      (float*)d_out, W);
}

// Round 7
// 921.442 us; speedup vs baseline: 1.9032x; 1.1668x over previous
//
#include <hip/hip_runtime.h>
#include <cmath>
#include <complex>
#include <algorithm>

#define N_NODES  32768
#define FEAT_DIM 480
#define TMUL     224
#define NB       4
#define ST       3328   // element count; LDS = ST elems, each elem = 4 nodes x bf16 = 8B (2 uints)

// element offsets (same map as f32 version)
#define F0O 0
#define F1O 128
#define F2O 320
#define P0O 480
#define P1O 608
#define P2O 800
#define C0O 960
#define C1O 1184
#define C2O 2048
#define Q0O 960
#define Q1O 1088
#define Q2O 1280
#define INVO 1440
#define HO   1664
#define GO   1888

// A-fragment staging buffer: [16 rows][240 cols] bf16 (rows 4..15 zeroed once)
#define FSTR 240

typedef float f32x4 __attribute__((ext_vector_type(4)));
typedef short short8 __attribute__((ext_vector_type(8)));

__device__ __forceinline__ float siluf(float x){ return x * (1.0f/(1.0f + __expf(-x))); }
__device__ __forceinline__ f32x4 silu4(f32x4 x){
  f32x4 r; r.x=siluf(x.x); r.y=siluf(x.y); r.z=siluf(x.z); r.w=siluf(x.w); return r;
}
__device__ __forceinline__ f32x4 sqrt4(f32x4 x){
  f32x4 r; r.x=sqrtf(x.x); r.y=sqrtf(x.y); r.z=sqrtf(x.z); r.w=sqrtf(x.w); return r;
}

// ---- bf16 pack/unpack (RNE; finite values only) ----
__device__ __forceinline__ float bfh(ushort h){ return __uint_as_float(((uint)h)<<16); }
__device__ __forceinline__ ushort f2bf(float f){
  uint u=__float_as_uint(f); return (ushort)((u + 0x7fffu + ((u>>16)&1u))>>16);
}
__device__ __forceinline__ f32x4 X0q(uint4 q){
  f32x4 r = {__uint_as_float(q.x<<16), __uint_as_float(q.x&0xffff0000u),
             __uint_as_float(q.y<<16), __uint_as_float(q.y&0xffff0000u)};
  return r;
}
__device__ __forceinline__ f32x4 X1q(uint4 q){
  f32x4 r = {__uint_as_float(q.z<<16), __uint_as_float(q.z&0xffff0000u),
             __uint_as_float(q.w<<16), __uint_as_float(q.w&0xffff0000u)};
  return r;
}
__device__ __forceinline__ f32x4 ldE(const uint* __restrict__ Lb, int e){
  uint2 q = *(const uint2*)&Lb[e*2];
  f32x4 r = {__uint_as_float(q.x<<16), __uint_as_float(q.x&0xffff0000u),
             __uint_as_float(q.y<<16), __uint_as_float(q.y&0xffff0000u)};
  return r;
}
__device__ __forceinline__ void stE(uint* __restrict__ Lb, int e, f32x4 x){
  uint2 q = { (uint)f2bf(x.x) | ((uint)f2bf(x.y)<<16),
              (uint)f2bf(x.z) | ((uint)f2bf(x.w)<<16) };
  *(uint2*)&Lb[e*2] = q;
}

struct W3Pack { float v[363]; };

// ------------------------- host: exact Wigner-3j (mirrors reference) -------------------------
static double factd(int n){ double f=1.0; for(int i=2;i<=n;++i) f*=(double)i; return f; }

static double su2_cg(int j1,int j2,int j3,int m1,int m2,int m3){
  if (m1+m2 != m3) return 0.0;
  double pref = std::sqrt((2.0*j3+1.0)*factd(j3+j1-j2)*factd(j3-j1+j2)*factd(j1+j2-j3)/factd(j1+j2+j3+1));
  pref *= std::sqrt(factd(j3+m3)*factd(j3-m3)*factd(j1-m1)*factd(j1+m1)*factd(j2-m2)*factd(j2+m2));
  double s=0.0;
  int vmin = std::max(0, std::max(j2-j3-m1, j1-j3+m2));
  int vmax = std::min(j2+m2, std::min(j1-m1, j1+j2-j3));
  for (int v=vmin; v<=vmax; ++v){
    double d = factd(v)*factd(j1+j2-j3-v)*factd(j1-m1-v)*factd(j2+m2-v)*factd(j3-j2+m1+v)*factd(j3-j1-m2+v);
    s += ((v&1)? -1.0 : 1.0)/d;
  }
  return pref*s;
}

typedef std::complex<double> cd;

static void qmat(int l, cd* q){
  int d=2*l+1;
  for (int a=0;a<d*d;++a) q[a]=cd(0,0);
  double is2 = 1.0/std::sqrt(2.0);
  for (int m=-l; m<0; ++m){
    int am=-m;
    q[(l+m)*d + (l+am)] = cd(is2,0);
    q[(l+m)*d + (l-am)] = cd(0,-is2);
  }
  q[l*d+l] = cd(1,0);
  for (int m=1;m<=l;++m){
    double sg = (m&1)? -1.0:1.0;
    q[(l+m)*d + (l+m)] = cd(sg*is2,0);
    q[(l+m)*d + (l-m)] = cd(0,sg*is2);
  }
  cd f = (l==0)? cd(1,0) : (l==1? cd(0,-1) : cd(-1,0)); // (-i)^l for l<=2
  for (int a=0;a<d*d;++a) q[a]*=f;
}

static void wigner3j(int l1,int l2,int l3, float* out){
  int d1=2*l1+1,d2=2*l2+1,d3=2*l3+1;
  double Cc[5][5][5] = {};
  for (int m1=-l1;m1<=l1;++m1) for (int m2=-l2;m2<=l2;++m2){
    int m3=m1+m2;
    if (m3>=-l3 && m3<=l3) Cc[l1+m1][l2+m2][l3+m3] = su2_cg(l1,l2,l3,m1,m2,m3);
  }
  cd q1[25],q2[25],q3[25];
  qmat(l1,q1); qmat(l2,q2); qmat(l3,q3);
  double re[125], im[125];
  double nr=0, ni=0;
  for (int i=0;i<d1;++i) for (int j=0;j<d2;++j) for (int k=0;k<d3;++k){
    cd s(0,0);
    for (int a=0;a<d1;++a) for (int b=0;b<d2;++b) for (int c=0;c<d3;++c){
      double cc = Cc[a][b][c];
      if (cc != 0.0) s += q1[a*d1+i]*q2[b*d2+j]*std::conj(q3[c*d3+k])*cc;
    }
    int o=(i*d2+j)*d3+k;
    re[o]=s.real(); im[o]=s.imag();
    nr += s.real()*s.real(); ni += s.imag()*s.imag();
  }
  bool useRe = std::sqrt(nr) >= std::sqrt(ni);
  double nrm = std::sqrt(useRe? nr : ni);
  for (int o=0;o<d1*d2*d3;++o) out[o] = (float)((useRe? re[o] : im[o]) / nrm);
}

static W3Pack build_w3(){
  W3Pack W;
  wigner3j(0,0,0, W.v+0);
  wigner3j(0,1,1, W.v+1);
  wigner3j(0,2,2, W.v+10);
  wigner3j(1,0,1, W.v+35);
  wigner3j(1,1,0, W.v+44);
  wigner3j(1,1,2, W.v+53);
  wigner3j(1,2,1, W.v+98);
  wigner3j(2,0,2, W.v+143);
  wigner3j(2,1,1, W.v+168);
  wigner3j(2,2,0, W.v+213);
  wigner3j(2,2,2, W.v+238);
  return W;
}

// ------------------------- device: tpw regroup (COLUMN-major = wave-coalesced, scale folded) -------------------------
__global__ __launch_bounds__(256) void prep_tpw(const float* __restrict__ tpw, float* __restrict__ wt)
{
  const int t = blockIdx.x*256 + threadIdx.x;
  if (t >= 55296) return;
  float v;
  if (t < 28672) {
    const int vv = t / 224, r = t - vv*224;
    int off, u;
    if (r < 128)      { off = 0;     u = r; }
    else if (r < 192) { off = 28672; u = r-128; }
    else              { off = 47104; u = r-192; }
    v = tpw[off + u*128 + vv] * 0.08838834764831845f;   // 1/sqrt(128)
  } else if (t < 47104) {
    const int t2 = t-28672; const int vv = t2/288, r = t2 - vv*288;
    int off, u;
    if (r < 128)      { off = 16384; u = r; }
    else if (r < 192) { off = 36864; u = r-128; }
    else if (r < 256) { off = 40960; u = r-192; }
    else              { off = 51200; u = r-256; }
    v = tpw[off + u*64 + vv] * 0.125f;                   // 1/sqrt(64)
  } else {
    const int t3 = t-47104; const int vv = t3/256, r = t3 & 255;
    int off, u;
    if (r < 128)      { off = 24576; u = r; }
    else if (r < 192) { off = 45056; u = r-128; }
    else if (r < 224) { off = 53248; u = r-192; }
    else              { off = 54272; u = r-224; }
    v = tpw[off + u*32 + vv] * 0.17677669529663687f;     // 1/sqrt(32)
  }
  wt[t] = v;
}

// ------------------------- device: gate-MLP weights -> bf16 MFMA B-fragment layout -------------------------
// wb[mat][((kt*14+ct)*64 + lane)*8 + e] = bf16( w[k][c] ), k = kt*32 + (lane>>4)*8 + e, c = ct*16 + (lane&15)
// mats: 0=pgw1, 1=pgw2, 2=qgw1, 3=qgw2  (each 224x224 row-major [in][out])
__global__ __launch_bounds__(256) void prep_mlp(
  const float* __restrict__ pgw1, const float* __restrict__ pgw2,
  const float* __restrict__ qgw1, const float* __restrict__ qgw2,
  ushort* __restrict__ wb)
{
  const int t = blockIdx.x*256 + threadIdx.x;
  if (t >= 4*50176) return;
  const int mat = t / 50176, s = t - mat*50176;
  const float* src = (mat==0)? pgw1 : (mat==1)? pgw2 : (mat==2)? qgw1 : qgw2;
  const int e = s & 7, l = (s>>3) & 63, q = s >> 9;
  const int ct = q % 14, kt = q / 14;
  const int k = kt*32 + (l>>4)*8 + e;
  const int c = ct*16 + (l&15);
  wb[t] = f2bf(src[k*224 + c]);
}

// ------------------------- bf16-LDS column matvec: 1 ds_read_b128 = 2 elems x 4 nodes -------------------------
template<int N>
__device__ __forceinline__ f32x4 matcolB(const float* __restrict__ Wg, const int wstride, const int col,
                                         const uint* __restrict__ Lb, const int inbase)
{
  f32x4 a0={}, a1={}, a2={}, a3={};
  const float* wp = Wg + col;
  #pragma unroll 2
  for (int u=0; u<N; u+=4) {
    const float wA = wp[(u+0)*wstride];
    const float wB = wp[(u+1)*wstride];
    const float wC = wp[(u+2)*wstride];
    const float wD = wp[(u+3)*wstride];
    const uint4 qa = *(const uint4*)&Lb[(inbase+u)*2];
    const uint4 qb = *(const uint4*)&Lb[(inbase+u+2)*2];
    a0 += X0q(qa)*wA;
    a1 += X1q(qa)*wB;
    a2 += X0q(qb)*wC;
    a3 += X1q(qb)*wD;
  }
  return (a0+a1)+(a2+a3);
}

// t-stage: NJ components share one coalesced weight column; JS = LDS elem stride between components
template<int NJ, int M2, int JS>
__device__ __forceinline__ void tstageB(const float* __restrict__ wcol, const int wstride,
                                        const uint* __restrict__ Lb, const int pbase,
                                        f32x4 (&t)[NJ])
{
  f32x4 a0[NJ], a1[NJ];
  #pragma unroll
  for (int j=0;j<NJ;++j){ a0[j]=(f32x4){}; a1[j]=(f32x4){}; }
  #pragma unroll 2
  for (int v=0; v<M2; v+=2) {
    const float wA = wcol[v*wstride];
    const float wB = wcol[(v+1)*wstride];
    #pragma unroll
    for (int j=0;j<NJ;++j) {
      const uint4 q = *(const uint4*)&Lb[(pbase + j*JS + v)*2];
      a0[j] += X0q(q)*wA;
      a1[j] += X1q(q)*wB;
    }
  }
  #pragma unroll
  for (int j=0;j<NJ;++j) t[j] = a0[j]+a1[j];
}

// ------------------------- normgate: inv -> wave mean/var -> MFMA MLP pair -> G -------------------------
// MLPs as mfma_f32_16x16x32_bf16, M=4 nodes (rows 4..15 of A zero).
// A/B loaded with MATCHING lane->(row/col, k-position) maps: row/col = lane&15, kpos = (lane>>4)*8+e.
// D layout (HW-verified): col = lane&15, row = (lane>>4)*4 + reg -> lanes 0..15 hold all 4 nodes.
__device__ __forceinline__ void normgateB(uint* __restrict__ Lb, ushort* __restrict__ Lb16,
                                          ushort* __restrict__ FT16, f32x4* __restrict__ sRed, const int c,
                                          const int B0, const int B1, const int B2,
                                          const ushort* __restrict__ wb1, const float* __restrict__ gb1,
                                          const ushort* __restrict__ wb2, const float* __restrict__ gb2)
{
  if (c < 128) {
    const uint2 q = *(const uint2*)&Lb[(B0+c)*2];       // bf16->bf16 copy, lossless
    *(uint2*)&Lb[(INVO+c)*2] = q;
  } else if (c < 192) {
    const int v = c-128;
    f32x4 s = {1e-12f,1e-12f,1e-12f,1e-12f};
    #pragma unroll
    for (int i=0;i<3;++i){ const f32x4 x = ldE(Lb, B1+i*64+v); s += x*x; }
    stE(Lb, INVO+c, sqrt4(s));
  } else if (c < 224) {
    const int v = c-192;
    f32x4 s = {1e-12f,1e-12f,1e-12f,1e-12f};
    #pragma unroll
    for (int i=0;i<5;++i){ const f32x4 x = ldE(Lb, B2+i*32+v); s += x*x; }
    stE(Lb, INVO+c, sqrt4(s));
  }
  __syncthreads();
  {
    const int w = c>>6, l = c&63;   // wave w <-> node w
    float s=0.f, s2=0.f, x;
    x = bfh(Lb16[(INVO+l)*4+w]);      s+=x; s2+=x*x;
    x = bfh(Lb16[(INVO+64+l)*4+w]);   s+=x; s2+=x*x;
    x = bfh(Lb16[(INVO+128+l)*4+w]);  s+=x; s2+=x*x;
    if (l < 32) { x = bfh(Lb16[(INVO+192+l)*4+w]); s+=x; s2+=x*x; }
    #pragma unroll
    for (int off=32; off>=1; off>>=1) {
      s  += __shfl_xor(s,  off, 64);
      s2 += __shfl_xor(s2, off, 64);
    }
    if (l==0) {
      const float m = s*(1.f/224.f);
      ((float*)&sRed[0])[w] = m;
      ((float*)&sRed[1])[w] = rsqrtf(s2*(1.f/224.f) - m*m + 1e-5f);
    }
  }
  __syncthreads();
  if (c < TMUL) {
    const f32x4 x = ldE(Lb, INVO+c);
    const f32x4 vn = (x - sRed[0])*sRed[1];
    FT16[0*FSTR+c]=f2bf(vn.x); FT16[1*FSTR+c]=f2bf(vn.y);
    FT16[2*FSTR+c]=f2bf(vn.z); FT16[3*FSTR+c]=f2bf(vn.w);
  }
  __syncthreads();                  // vn fragment buffer complete

  const int wv = c>>6, ln = c&63;
  // ---- MLP1: vn @ wb1 (K=224 -> 7 kt; N=224 -> 14 ct, wave wv does ct = wv,wv+4,wv+8,(wv+12)) ----
  f32x4 m0={}, m1={}, m2={}, m3={};
  #pragma unroll
  for (int kt=0; kt<7; ++kt) {
    const short8 A = *(const short8*)&FT16[(ln&15)*FSTR + kt*32 + (ln>>4)*8];
    { const short8 B = *(const short8*)&wb1[((kt*14 + wv    )*64 + ln)*8];
      m0 = __builtin_amdgcn_mfma_f32_16x16x32_bf16(A, B, m0, 0, 0, 0); }
    { const short8 B = *(const short8*)&wb1[((kt*14 + wv + 4)*64 + ln)*8];
      m1 = __builtin_amdgcn_mfma_f32_16x16x32_bf16(A, B, m1, 0, 0, 0); }
    { const short8 B = *(const short8*)&wb1[((kt*14 + wv + 8)*64 + ln)*8];
      m2 = __builtin_amdgcn_mfma_f32_16x16x32_bf16(A, B, m2, 0, 0, 0); }
    if (wv < 2) {
      const short8 B = *(const short8*)&wb1[((kt*14 + wv +12)*64 + ln)*8];
      m3 = __builtin_amdgcn_mfma_f32_16x16x32_bf16(A, B, m3, 0, 0, 0);
    }
  }
  __syncthreads();                  // all reads of FT(vn) done
  if (ln < 16) {
    { const int ch=(wv   )*16+ln; const f32x4 h=silu4(m0+gb1[ch]);
      FT16[0*FSTR+ch]=f2bf(h.x); FT16[1*FSTR+ch]=f2bf(h.y); FT16[2*FSTR+ch]=f2bf(h.z); FT16[3*FSTR+ch]=f2bf(h.w); }
    { const int ch=(wv+4 )*16+ln; const f32x4 h=silu4(m1+gb1[ch]);
      FT16[0*FSTR+ch]=f2bf(h.x); FT16[1*FSTR+ch]=f2bf(h.y); FT16[2*FSTR+ch]=f2bf(h.z); FT16[3*FSTR+ch]=f2bf(h.w); }
    { const int ch=(wv+8 )*16+ln; const f32x4 h=silu4(m2+gb1[ch]);
      FT16[0*FSTR+ch]=f2bf(h.x); FT16[1*FSTR+ch]=f2bf(h.y); FT16[2*FSTR+ch]=f2bf(h.z); FT16[3*FSTR+ch]=f2bf(h.w); }
    if (wv < 2) {
      const int ch=(wv+12)*16+ln; const f32x4 h=silu4(m3+gb1[ch]);
      FT16[0*FSTR+ch]=f2bf(h.x); FT16[1*FSTR+ch]=f2bf(h.y); FT16[2*FSTR+ch]=f2bf(h.z); FT16[3*FSTR+ch]=f2bf(h.w); }
  }
  __syncthreads();                  // FT now holds H
  // ---- MLP2: H @ wb2 ----
  f32x4 g0={}, g1={}, g2={}, g3={};
  #pragma unroll
  for (int kt=0; kt<7; ++kt) {
    const short8 A = *(const short8*)&FT16[(ln&15)*FSTR + kt*32 + (ln>>4)*8];
    { const short8 B = *(const short8*)&wb2[((kt*14 + wv    )*64 + ln)*8];
      g0 = __builtin_amdgcn_mfma_f32_16x16x32_bf16(A, B, g0, 0, 0, 0); }
    { const short8 B = *(const short8*)&wb2[((kt*14 + wv + 4)*64 + ln)*8];
      g1 = __builtin_amdgcn_mfma_f32_16x16x32_bf16(A, B, g1, 0, 0, 0); }
    { const short8 B = *(const short8*)&wb2[((kt*14 + wv + 8)*64 + ln)*8];
      g2 = __builtin_amdgcn_mfma_f32_16x16x32_bf16(A, B, g2, 0, 0, 0); }
    if (wv < 2) {
      const short8 B = *(const short8*)&wb2[((kt*14 + wv +12)*64 + ln)*8];
      g3 = __builtin_amdgcn_mfma_f32_16x16x32_bf16(A, B, g3, 0, 0, 0);
    }
  }
  if (ln < 16) {                    // G -> node-minor (no FT conflict)
    { const int ch=(wv   )*16+ln; stE(Lb, GO+ch, silu4(g0+gb2[ch])); }
    { const int ch=(wv+4 )*16+ln; stE(Lb, GO+ch, silu4(g1+gb2[ch])); }
    { const int ch=(wv+8 )*16+ln; stE(Lb, GO+ch, silu4(g2+gb2[ch])); }
    if (wv < 2) { const int ch=(wv+12)*16+ln; stE(Lb, GO+ch, silu4(g3+gb2[ch])); }
  }
  __syncthreads();                  // G visible to all threads
}

// ------------------------- CG rows, groups B and C -------------------------
__device__ __forceinline__ void cg_rowB(const int r, const float* __restrict__ wt,
                                        const W3Pack& W, uint* __restrict__ Lb)
{
  f32x4 tb[3];
  tstageB<3,64,64>(wt + 28672 + r, 288, Lb, P1O, tb);
  if (r < 128) {                       // p2 (0,1,1): out C1 row r
    const f32x4 f = ldE(Lb, F0O+r);
    #pragma unroll
    for (int k=0;k<3;++k) {
      f32x4 s = tb[0]*W.v[1+0*3+k] + tb[1]*W.v[1+1*3+k] + tb[2]*W.v[1+2*3+k];
      stE(Lb, C1O+k*288+r, f*s);
    }
  } else if (r < 192) {                // p5 (1,1,0): out C0 row 128+u
    const int u=r-128;
    f32x4 y = {};
    #pragma unroll
    for (int i=0;i<3;++i) {
      f32x4 s = tb[0]*W.v[44+i*3+0] + tb[1]*W.v[44+i*3+1] + tb[2]*W.v[44+i*3+2];
      y += ldE(Lb, F1O+i*64+u)*s;
    }
    stE(Lb, C0O+128+u, y);
  } else if (r < 256) {                // p6 (1,1,2): out C2 row 128+u
    const int u=r-192;
    f32x4 f[3];
    #pragma unroll
    for (int i=0;i<3;++i) f[i]=ldE(Lb, F1O+i*64+u);
    #pragma unroll
    for (int k=0;k<5;++k) {
      f32x4 y = {};
      #pragma unroll
      for (int i=0;i<3;++i) {
        f32x4 s = tb[0]*W.v[53+(i*3+0)*5+k] + tb[1]*W.v[53+(i*3+1)*5+k] + tb[2]*W.v[53+(i*3+2)*5+k];
        y += f[i]*s;
      }
      stE(Lb, C2O+k*256+128+u, y);
    }
  } else {                             // p9 (2,1,1): out C1 row 256+u
    const int u=r-256;
    f32x4 f[5];
    #pragma unroll
    for (int i=0;i<5;++i) f[i]=ldE(Lb, F2O+i*32+u);
    #pragma unroll
    for (int k=0;k<3;++k) {
      f32x4 y = {};
      #pragma unroll
      for (int i=0;i<5;++i) {
        f32x4 s = tb[0]*W.v[168+(i*3+0)*3+k] + tb[1]*W.v[168+(i*3+1)*3+k] + tb[2]*W.v[168+(i*3+2)*3+k];
        y += f[i]*s;
      }
      stE(Lb, C1O+k*288+256+u, y);
    }
  }
}

__device__ __forceinline__ void cg_rowC(const int r, const float* __restrict__ wt,
                                        const W3Pack& W, uint* __restrict__ Lb)
{
  f32x4 tc[5];
  tstageB<5,32,32>(wt + 47104 + r, 256, Lb, P2O, tc);
  if (r < 128) {                       // p3 (0,2,2): out C2 row r
    const f32x4 f = ldE(Lb, F0O+r);
    #pragma unroll
    for (int k=0;k<5;++k) {
      f32x4 s = {};
      #pragma unroll
      for (int j=0;j<5;++j) s += tc[j]*W.v[10+j*5+k];
      stE(Lb, C2O+k*256+r, f*s);
    }
  } else if (r < 192) {                // p7 (1,2,1): out C1 row 192+u
    const int u=r-128;
    f32x4 f[3];
    #pragma unroll
    for (int i=0;i<3;++i) f[i]=ldE(Lb, F1O+i*64+u);
    #pragma unroll
    for (int k=0;k<3;++k) {
      f32x4 y = {};
      #pragma unroll
      for (int i=0;i<3;++i) {
        f32x4 s = {};
        #pragma unroll
        for (int j=0;j<5;++j) s += tc[j]*W.v[98+(i*5+j)*3+k];
        y += f[i]*s;
      }
      stE(Lb, C1O+k*288+192+u, y);
    }
  } else if (r < 224) {                // p10 (2,2,0): out C0 row 192+u
    const int u=r-192;
    f32x4 y = {};
    #pragma unroll
    for (int i=0;i<5;++i) {
      f32x4 s = {};
      #pragma unroll
      for (int j=0;j<5;++j) s += tc[j]*W.v[213+i*5+j];
      y += ldE(Lb, F2O+i*32+u)*s;
    }
    stE(Lb, C0O+192+u, y);
  } else {                             // p11 (2,2,2): out C2 row 224+u
    const int u=r-224;
    f32x4 f[5];
    #pragma unroll
    for (int i=0;i<5;++i) f[i]=ldE(Lb, F2O+i*32+u);
    #pragma unroll
    for (int k=0;k<5;++k) {
      f32x4 y = {};
      #pragma unroll
      for (int i=0;i<5;++i) {
        f32x4 s = {};
        #pragma unroll
        for (int j=0;j<5;++j) s += tc[j]*W.v[238+(i*5+j)*5+k];
        y += f[i]*s;
      }
      stE(Lb, C2O+k*256+224+u, y);
    }
  }
}

// ------------------------- fused kernel: NB nodes per block, bf16 node-minor LDS + MFMA MLPs -------------------------
__global__ __launch_bounds__(256, 4) void fused4(
  const float* __restrict__ feat,
  const float* __restrict__ w0, const float* __restrict__ w1, const float* __restrict__ w2,
  const float* __restrict__ pgb1, const float* __restrict__ pgb2,
  const float* __restrict__ wt, const ushort* __restrict__ wb,
  const float* __restrict__ pw0, const float* __restrict__ pw1, const float* __restrict__ pw2,
  const float* __restrict__ qgb1, const float* __restrict__ qgb2,
  float* __restrict__ outp, const W3Pack W)
{
  __shared__ uint LbU[ST*2];          // 26624 B
  __shared__ ushort FT16[16*FSTR];    // 7680 B  (A-fragment staging: vn/H, rows 4..15 zero)
  __shared__ f32x4 sRed[2];           // mean, rstd (f32, per node)
  uint* Lb = LbU;
  ushort* Lb16 = (ushort*)LbU;
  const int c = threadIdx.x;
  const size_t gbase = (size_t)blockIdx.x * (FEAT_DIM*NB);

  // ---- zero FT (one-time; rows 0-3 get overwritten before any read) ----
  {
    uint* FTz = (uint*)FT16;
    #pragma unroll
    for (int t=c; t<16*FSTR/2; t+=256) FTz[t] = 0;
  }

  // ---- load + de-interleave (component-major elems, node-minor bf16) ----
  for (int t=c; t<FEAT_DIM*NB; t+=256) {
    const float val = feat[gbase + t];
    const int nb = t / FEAT_DIM;
    const int ch = t - nb*FEAT_DIM;
    int loc;
    if (ch < 128) loc = F0O + ch;
    else if (ch < 320) { const int q = ch-128; const int u = q/3; loc = F1O + (q-u*3)*64 + u; }
    else               { const int q = ch-320; const int u = q/5; loc = F2O + (q-u*5)*32 + u; }
    Lb16[loc*4 + nb] = f2bf(val);
  }
  __syncthreads();

  // ---- pre-linear (slot-balanced; coalesced original-layout weights) ----
  {
    f32x4 a1, a2 = {};
    int o1, o2=-1; float s1, s2s=0.f;
    if (c < 128) { a1 = matcolB<128>(w0, 128, c, Lb, F0O); o1 = P0O+c; s1 = 0.08838834764831845f; }
    else { const int q=c-128; const int i=q>>6, v=q&63;
           a1 = matcolB<64>(w1, 64, v, Lb, F1O+i*64); o1 = P1O+i*64+v; s1 = 0.125f; }
    if (c < 64) { a2 = matcolB<64>(w1, 64, c, Lb, F1O+128); o2 = P1O+128+c; s2s = 0.125f; }
    else if (c < 224) { const int q=c-64; const int i=q>>5, v=q&31;
           a2 = matcolB<32>(w2, 32, v, Lb, F2O+i*32); o2 = P2O+i*32+v; s2s = 0.17677669529663687f; }
    stE(Lb, o1, a1*s1);
    if (o2 >= 0) stE(Lb, o2, a2*s2s);
  }
  __syncthreads();

  // ---- pre normgate (MFMA MLPs) + gate P in place ----
  normgateB(Lb, Lb16, FT16, sRed, c, P0O, P1O, P2O, wb, pgb1, wb+50176, pgb2);
  if (c < 128) {
    stE(Lb, P0O+c, ldE(Lb,P0O+c)*ldE(Lb,GO+c));
  } else if (c < 192) {
    const int v=c-128; const f32x4 g=ldE(Lb,GO+c);
    #pragma unroll
    for (int i=0;i<3;++i) stE(Lb, P1O+i*64+v, ldE(Lb,P1O+i*64+v)*g);
  } else if (c < 224) {
    const int v=c-192; const f32x4 g=ldE(Lb,GO+c);
    #pragma unroll
    for (int i=0;i<5;++i) stE(Lb, P2O+i*32+v, ldE(Lb,P2O+i*32+v)*g);
  }
  __syncthreads();   // P gated

  // ---- CG coupling: group A (thread=row; t = matcolB over P0) ----
  if (c < 224) {
    const f32x4 tA = matcolB<128>(wt, 224, c, Lb, P0O);
    if (c < 128) {                     // p1 (0,0,0): out C0 row c
      stE(Lb, C0O+c, ldE(Lb,F0O+c)*tA*W.v[0]);
    } else if (c < 192) {              // p4 (1,0,1): out C1 row 128+u
      const int u=c-128;
      const f32x4 f0=ldE(Lb,F1O+u), f1=ldE(Lb,F1O+64+u), f2=ldE(Lb,F1O+128+u);
      #pragma unroll
      for (int k=0;k<3;++k)
        stE(Lb, C1O+k*288+128+u, tA*(f0*W.v[35+k] + f1*W.v[38+k] + f2*W.v[41+k]));
    } else {                           // p8 (2,0,2): out C2 row 192+u
      const int u=c-192;
      f32x4 f[5];
      #pragma unroll
      for (int i=0;i<5;++i) f[i]=ldE(Lb,F2O+i*32+u);
      #pragma unroll
      for (int k=0;k<5;++k) {
        f32x4 y = {};
        #pragma unroll
        for (int i=0;i<5;++i) y += f[i]*W.v[143+i*5+k];
        stE(Lb, C2O+k*256+192+u, tA*y);
      }
    }
  }
  // groups B (288 rows) and C (256 rows)
  cg_rowB(c, wt, W, Lb);
  if (c >= 224) cg_rowB(c+32, wt, W, Lb);
  cg_rowC(c, wt, W, Lb);
  __syncthreads();

  // ---- post-linear (reg-staged: Q overlays C head, write after all C reads) ----
  {
    f32x4 pa, pb = {};
    int po1, po2=-1; float ps1, ps2=0.f;
    if (c < 128) { pa = matcolB<224>(pw0, 128, c, Lb, C0O); po1 = Q0O+c; ps1 = 0.06681531047810609f; }
    else { const int q=c-128; const int i=q>>6, v=q&63;
           pa = matcolB<288>(pw1, 64, v, Lb, C1O+i*288); po1 = Q1O+i*64+v; ps1 = 0.05892556509887896f; }
    if (c < 64) { pb = matcolB<288>(pw1, 64, c, Lb, C1O+2*288); po2 = Q1O+128+c; ps2 = 0.05892556509887896f; }
    else if (c < 224) { const int q=c-64; const int i=q>>5, v=q&31;
           pb = matcolB<256>(pw2, 32, v, Lb, C2O+i*256); po2 = Q2O+i*32+v; ps2 = 0.0625f; }
    __syncthreads();   // all C reads complete before Q overwrite
    stE(Lb, po1, pa*ps1);
    if (po2 >= 0) stE(Lb, po2, pb*ps2);
  }
  __syncthreads();

  // ---- post normgate (MFMA MLPs) ----
  normgateB(Lb, Lb16, FT16, sRed, c, Q0O, Q1O, Q2O, wb+100352, qgb1, wb+150528, qgb2);

  // ---- final: out = feat(f32, re-read) + pre_gated + post*G (coalesced) ----
  for (int t=c; t<FEAT_DIM*NB; t+=256) {
    const int nb = t / FEAT_DIM;
    const int ch = t - nb*FEAT_DIM;
    float pre, q, g;
    if (ch < 128) {
      pre = bfh(Lb16[(P0O+ch)*4+nb]);
      q   = bfh(Lb16[(Q0O+ch)*4+nb]);
      g   = bfh(Lb16[(GO+ch)*4+nb]);
    } else if (ch < 320) {
      const int qq=ch-128; const int u=qq/3; const int o=(qq-u*3)*64+u;
      pre = bfh(Lb16[(P1O+o)*4+nb]);
      q   = bfh(Lb16[(Q1O+o)*4+nb]);
      g   = bfh(Lb16[(GO+128+u)*4+nb]);
    } else {
      const int qq=ch-320; const int u=qq/5; const int o=(qq-u*5)*32+u;
      pre = bfh(Lb16[(P2O+o)*4+nb]);
      q   = bfh(Lb16[(Q2O+o)*4+nb]);
      g   = bfh(Lb16[(GO+192+u)*4+nb]);
    }
    outp[gbase + t] = feat[gbase + t] + pre + q*g;
  }
}

// ------------------------- launch -------------------------
extern "C" void kernel_launch(void* const* d_in, const int* in_sizes, int n_in,
                              void* d_out, int out_size, void* d_ws, size_t ws_size,
                              hipStream_t stream)
{
  (void)in_sizes; (void)n_in; (void)out_size; (void)ws_size;
  const float* feat  = (const float*)d_in[0];
  const float* prw0  = (const float*)d_in[1];
  const float* prw1  = (const float*)d_in[2];
  const float* prw2  = (const float*)d_in[3];
  const float* pngw1 = (const float*)d_in[4];
  const float* pngb1 = (const float*)d_in[5];
  const float* pngw2 = (const float*)d_in[6];
  const float* pngb2 = (const float*)d_in[7];
  const float* tpw   = (const float*)d_in[8];
  const float* pow0  = (const float*)d_in[9];
  const float* pow1  = (const float*)d_in[10];
  const float* pow2  = (const float*)d_in[11];
  const float* qngw1 = (const float*)d_in[12];
  const float* qngb1 = (const float*)d_in[13];
  const float* qngw2 = (const float*)d_in[14];
  const float* qngb2 = (const float*)d_in[15];

  float*  wt = (float*)d_ws;                             // 55296 f32: regrouped tpw
  ushort* wb = (ushort*)((char*)d_ws + 55296*sizeof(float)); // 4*50176 bf16: gate MLPs, frag layout

  W3Pack W = build_w3();               // host-only, identical every call

  prep_tpw<<<dim3(216), dim3(256), 0, stream>>>(tpw, wt);
  prep_mlp<<<dim3(784), dim3(256), 0, stream>>>(pngw1, pngw2, qngw1, qngw2, wb);

  fused4<<<dim3(N_NODES/NB), dim3(256), 0, stream>>>(
      feat, prw0, prw1, prw2, pngb1, pngb2,
      wt, wb, pow0, pow1, pow2, qngb1, qngb2,
      (float*)d_out, W);
}

// Round 8
// 835.985 us; speedup vs baseline: 2.0977x; 1.1022x over previous
//
#include <hip/hip_runtime.h>
#include <cmath>
#include <complex>
#include <algorithm>

#define N_NODES  32768
#define FEAT_DIM 480
#define TMUL     224
#define NB       4

// node-minor LDS element offsets (each elem = 4 nodes x bf16 = 8B)
#define F0O 0
#define F1O 128
#define F2O 320
#define P0O 480
#define P1O 608
#define P2O 800
#define Q0O 960
#define Q1O 1088
#define Q2O 1280
#define INVO 1440
#define GO   1888
#define NMSZ 2112

// fragment staging buffer BF (ushort[16384] = 32KB), overlaid regions:
//  C0f @0     16x224   (alive CG -> post-linear)
//  C1f @3584  16x288
//  C2f @8192  32x256   (tile1 rows 16-19 = i=4)
//  FT  @0     16x240   (alive inside normgates only)
//  F0f @8192  16x128   (alive load -> pre-linear)
//  F1f @10240 16x64
//  F2f @11264 32x32    (tile1 rows 16-19 = i=4)
#define FSTR 240

typedef float f32x4 __attribute__((ext_vector_type(4)));
typedef short short8 __attribute__((ext_vector_type(8)));

__device__ __forceinline__ float siluf(float x){ return x * (1.0f/(1.0f + __expf(-x))); }
__device__ __forceinline__ f32x4 silu4(f32x4 x){
  f32x4 r; r.x=siluf(x.x); r.y=siluf(x.y); r.z=siluf(x.z); r.w=siluf(x.w); return r;
}
__device__ __forceinline__ f32x4 sqrt4(f32x4 x){
  f32x4 r; r.x=sqrtf(x.x); r.y=sqrtf(x.y); r.z=sqrtf(x.z); r.w=sqrtf(x.w); return r;
}

// ---- bf16 pack/unpack (RNE; finite values only) ----
__device__ __forceinline__ float bfh(ushort h){ return __uint_as_float(((uint)h)<<16); }
__device__ __forceinline__ ushort f2bf(float f){
  uint u=__float_as_uint(f); return (ushort)((u + 0x7fffu + ((u>>16)&1u))>>16);
}
__device__ __forceinline__ f32x4 X0q(uint4 q){
  f32x4 r = {__uint_as_float(q.x<<16), __uint_as_float(q.x&0xffff0000u),
             __uint_as_float(q.y<<16), __uint_as_float(q.y&0xffff0000u)};
  return r;
}
__device__ __forceinline__ f32x4 X1q(uint4 q){
  f32x4 r = {__uint_as_float(q.z<<16), __uint_as_float(q.z&0xffff0000u),
             __uint_as_float(q.w<<16), __uint_as_float(q.w&0xffff0000u)};
  return r;
}
__device__ __forceinline__ f32x4 ldE(const uint* __restrict__ Lb, int e){
  uint2 q = *(const uint2*)&Lb[e*2];
  f32x4 r = {__uint_as_float(q.x<<16), __uint_as_float(q.x&0xffff0000u),
             __uint_as_float(q.y<<16), __uint_as_float(q.y&0xffff0000u)};
  return r;
}
__device__ __forceinline__ void stE(uint* __restrict__ Lb, int e, f32x4 x){
  uint2 q = { (uint)f2bf(x.x) | ((uint)f2bf(x.y)<<16),
              (uint)f2bf(x.z) | ((uint)f2bf(x.w)<<16) };
  *(uint2*)&Lb[e*2] = q;
}
// store 4 nodes of y into frag rows row0..row0+3, column col
__device__ __forceinline__ void stF(ushort* __restrict__ p, int stride, int row0, int col, f32x4 y){
  p[(row0+0)*stride+col]=f2bf(y.x);
  p[(row0+1)*stride+col]=f2bf(y.y);
  p[(row0+2)*stride+col]=f2bf(y.z);
  p[(row0+3)*stride+col]=f2bf(y.w);
}

struct W3Pack { float v[363]; };

// ------------------------- host: exact Wigner-3j (mirrors reference) -------------------------
static double factd(int n){ double f=1.0; for(int i=2;i<=n;++i) f*=(double)i; return f; }

static double su2_cg(int j1,int j2,int j3,int m1,int m2,int m3){
  if (m1+m2 != m3) return 0.0;
  double pref = std::sqrt((2.0*j3+1.0)*factd(j3+j1-j2)*factd(j3-j1+j2)*factd(j1+j2-j3)/factd(j1+j2+j3+1));
  pref *= std::sqrt(factd(j3+m3)*factd(j3-m3)*factd(j1-m1)*factd(j1+m1)*factd(j2-m2)*factd(j2+m2));
  double s=0.0;
  int vmin = std::max(0, std::max(j2-j3-m1, j1-j3+m2));
  int vmax = std::min(j2+m2, std::min(j1-m1, j1+j2-j3));
  for (int v=vmin; v<=vmax; ++v){
    double d = factd(v)*factd(j1+j2-j3-v)*factd(j1-m1-v)*factd(j2+m2-v)*factd(j3-j2+m1+v)*factd(j3-j1-m2+v);
    s += ((v&1)? -1.0 : 1.0)/d;
  }
  return pref*s;
}

typedef std::complex<double> cd;

static void qmat(int l, cd* q){
  int d=2*l+1;
  for (int a=0;a<d*d;++a) q[a]=cd(0,0);
  double is2 = 1.0/std::sqrt(2.0);
  for (int m=-l; m<0; ++m){
    int am=-m;
    q[(l+m)*d + (l+am)] = cd(is2,0);
    q[(l+m)*d + (l-am)] = cd(0,-is2);
  }
  q[l*d+l] = cd(1,0);
  for (int m=1;m<=l;++m){
    double sg = (m&1)? -1.0:1.0;
    q[(l+m)*d + (l+m)] = cd(sg*is2,0);
    q[(l+m)*d + (l-m)] = cd(0,sg*is2);
  }
  cd f = (l==0)? cd(1,0) : (l==1? cd(0,-1) : cd(-1,0)); // (-i)^l for l<=2
  for (int a=0;a<d*d;++a) q[a]*=f;
}

static void wigner3j(int l1,int l2,int l3, float* out){
  int d1=2*l1+1,d2=2*l2+1,d3=2*l3+1;
  double Cc[5][5][5] = {};
  for (int m1=-l1;m1<=l1;++m1) for (int m2=-l2;m2<=l2;++m2){
    int m3=m1+m2;
    if (m3>=-l3 && m3<=l3) Cc[l1+m1][l2+m2][l3+m3] = su2_cg(l1,l2,l3,m1,m2,m3);
  }
  cd q1[25],q2[25],q3[25];
  qmat(l1,q1); qmat(l2,q2); qmat(l3,q3);
  double re[125], im[125];
  double nr=0, ni=0;
  for (int i=0;i<d1;++i) for (int j=0;j<d2;++j) for (int k=0;k<d3;++k){
    cd s(0,0);
    for (int a=0;a<d1;++a) for (int b=0;b<d2;++b) for (int c=0;c<d3;++c){
      double cc = Cc[a][b][c];
      if (cc != 0.0) s += q1[a*d1+i]*q2[b*d2+j]*std::conj(q3[c*d3+k])*cc;
    }
    int o=(i*d2+j)*d3+k;
    re[o]=s.real(); im[o]=s.imag();
    nr += s.real()*s.real(); ni += s.imag()*s.imag();
  }
  bool useRe = std::sqrt(nr) >= std::sqrt(ni);
  double nrm = std::sqrt(useRe? nr : ni);
  for (int o=0;o<d1*d2*d3;++o) out[o] = (float)((useRe? re[o] : im[o]) / nrm);
}

static W3Pack build_w3(){
  W3Pack W;
  wigner3j(0,0,0, W.v+0);
  wigner3j(0,1,1, W.v+1);
  wigner3j(0,2,2, W.v+10);
  wigner3j(1,0,1, W.v+35);
  wigner3j(1,1,0, W.v+44);
  wigner3j(1,1,2, W.v+53);
  wigner3j(1,2,1, W.v+98);
  wigner3j(2,0,2, W.v+143);
  wigner3j(2,1,1, W.v+168);
  wigner3j(2,2,0, W.v+213);
  wigner3j(2,2,2, W.v+238);
  return W;
}

// ------------------------- device: tpw regroup (COLUMN-major = wave-coalesced, scale folded) -------------------------
__global__ __launch_bounds__(256) void prep_tpw(const float* __restrict__ tpw, float* __restrict__ wt)
{
  const int t = blockIdx.x*256 + threadIdx.x;
  if (t >= 55296) return;
  float v;
  if (t < 28672) {
    const int vv = t / 224, r = t - vv*224;
    int off, u;
    if (r < 128)      { off = 0;     u = r; }
    else if (r < 192) { off = 28672; u = r-128; }
    else              { off = 47104; u = r-192; }
    v = tpw[off + u*128 + vv] * 0.08838834764831845f;   // 1/sqrt(128)
  } else if (t < 47104) {
    const int t2 = t-28672; const int vv = t2/288, r = t2 - vv*288;
    int off, u;
    if (r < 128)      { off = 16384; u = r; }
    else if (r < 192) { off = 36864; u = r-128; }
    else if (r < 256) { off = 40960; u = r-192; }
    else              { off = 51200; u = r-256; }
    v = tpw[off + u*64 + vv] * 0.125f;                   // 1/sqrt(64)
  } else {
    const int t3 = t-47104; const int vv = t3/256, r = t3 & 255;
    int off, u;
    if (r < 128)      { off = 24576; u = r; }
    else if (r < 192) { off = 45056; u = r-128; }
    else if (r < 224) { off = 53248; u = r-192; }
    else              { off = 54272; u = r-224; }
    v = tpw[off + u*32 + vv] * 0.17677669529663687f;     // 1/sqrt(32)
  }
  wt[t] = v;
}

// ------------------------- device: gate-MLP weights -> bf16 MFMA B-fragment layout -------------------------
__global__ __launch_bounds__(256) void prep_mlp(
  const float* __restrict__ pgw1, const float* __restrict__ pgw2,
  const float* __restrict__ qgw1, const float* __restrict__ qgw2,
  ushort* __restrict__ wb)
{
  const int t = blockIdx.x*256 + threadIdx.x;
  if (t >= 4*50176) return;
  const int mat = t / 50176, s = t - mat*50176;
  const float* src = (mat==0)? pgw1 : (mat==1)? pgw2 : (mat==2)? qgw1 : qgw2;
  const int e = s & 7, l = (s>>3) & 63, q = s >> 9;
  const int ct = q % 14, kt = q / 14;
  const int k = kt*32 + (l>>4)*8 + e;
  const int c = ct*16 + (l&15);
  wb[t] = f2bf(src[k*224 + c]);
}

// ------------------------- device: pre/post linear weights -> bf16 B-fragments (scales folded) -------------------------
// layout per matrix: wf[(tile*64 + lane)*8 + e] with tile = kt*NCT + ct; k=kt*32+(lane>>4)*8+e, c=ct*16+(lane&15)
// segments: w0f[0,16384) w1f[16384,20480) w2f[20480,21504) pw0f[21504,50176) pw1f[50176,68608) pw2f[68608,76800)
__global__ __launch_bounds__(256) void prep_lin(
  const float* __restrict__ w0, const float* __restrict__ w1, const float* __restrict__ w2,
  const float* __restrict__ pw0, const float* __restrict__ pw1, const float* __restrict__ pw2,
  ushort* __restrict__ wf)
{
  const int t = blockIdx.x*256 + threadIdx.x;
  if (t >= 76800) return;
  int s = t; const float* src; int ncols, nct; float sc;
  if      (t < 16384) { src=w0;  ncols=128; nct=8; sc=0.08838834764831845f; }
  else if (t < 20480) { s=t-16384; src=w1;  ncols=64;  nct=4; sc=0.125f; }
  else if (t < 21504) { s=t-20480; src=w2;  ncols=32;  nct=2; sc=0.17677669529663687f; }
  else if (t < 50176) { s=t-21504; src=pw0; ncols=128; nct=8; sc=0.06681531047810609f; }
  else if (t < 68608) { s=t-50176; src=pw1; ncols=64;  nct=4; sc=0.05892556509887896f; }
  else                { s=t-68608; src=pw2; ncols=32;  nct=2; sc=0.0625f; }
  const int e = s & 7, l = (s>>3) & 63, tile = s >> 9;
  const int ct = tile % nct, kt = tile / nct;
  const int k = kt*32 + (l>>4)*8 + e;
  const int c = ct*16 + (l&15);
  wf[t] = f2bf(src[k*ncols + c] * sc);
}

// ------------------------- bf16-LDS column matvec (node-minor input) -------------------------
template<int N>
__device__ __forceinline__ f32x4 matcolB(const float* __restrict__ Wg, const int wstride, const int col,
                                         const uint* __restrict__ Lb, const int inbase)
{
  f32x4 a0={}, a1={}, a2={}, a3={};
  const float* wp = Wg + col;
  #pragma unroll 2
  for (int u=0; u<N; u+=4) {
    const float wA = wp[(u+0)*wstride];
    const float wB = wp[(u+1)*wstride];
    const float wC = wp[(u+2)*wstride];
    const float wD = wp[(u+3)*wstride];
    const uint4 qa = *(const uint4*)&Lb[(inbase+u)*2];
    const uint4 qb = *(const uint4*)&Lb[(inbase+u+2)*2];
    a0 += X0q(qa)*wA;
    a1 += X1q(qa)*wB;
    a2 += X0q(qb)*wC;
    a3 += X1q(qb)*wD;
  }
  return (a0+a1)+(a2+a3);
}

// t-stage: NJ components share one coalesced weight column; JS = LDS elem stride between components
template<int NJ, int M2, int JS>
__device__ __forceinline__ void tstageB(const float* __restrict__ wcol, const int wstride,
                                        const uint* __restrict__ Lb, const int pbase,
                                        f32x4 (&t)[NJ])
{
  f32x4 a0[NJ], a1[NJ];
  #pragma unroll
  for (int j=0;j<NJ;++j){ a0[j]=(f32x4){}; a1[j]=(f32x4){}; }
  #pragma unroll 2
  for (int v=0; v<M2; v+=2) {
    const float wA = wcol[v*wstride];
    const float wB = wcol[(v+1)*wstride];
    #pragma unroll
    for (int j=0;j<NJ;++j) {
      const uint4 q = *(const uint4*)&Lb[(pbase + j*JS + v)*2];
      a0[j] += X0q(q)*wA;
      a1[j] += X1q(q)*wB;
    }
  }
  #pragma unroll
  for (int j=0;j<NJ;++j) t[j] = a0[j]+a1[j];
}

// ------------------------- normgate: inv -> wave mean/var -> MFMA MLP pair -> G -------------------------
__device__ __forceinline__ void normgateB(uint* __restrict__ Lb, ushort* __restrict__ Lb16,
                                          ushort* __restrict__ FT16, f32x4* __restrict__ sRed, const int c,
                                          const int B0, const int B1, const int B2,
                                          const ushort* __restrict__ wb1, const float* __restrict__ gb1,
                                          const ushort* __restrict__ wb2, const float* __restrict__ gb2)
{
  if (c < 128) {
    const uint2 q = *(const uint2*)&Lb[(B0+c)*2];       // bf16->bf16 copy, lossless
    *(uint2*)&Lb[(INVO+c)*2] = q;
  } else if (c < 192) {
    const int v = c-128;
    f32x4 s = {1e-12f,1e-12f,1e-12f,1e-12f};
    #pragma unroll
    for (int i=0;i<3;++i){ const f32x4 x = ldE(Lb, B1+i*64+v); s += x*x; }
    stE(Lb, INVO+c, sqrt4(s));
  } else if (c < 224) {
    const int v = c-192;
    f32x4 s = {1e-12f,1e-12f,1e-12f,1e-12f};
    #pragma unroll
    for (int i=0;i<5;++i){ const f32x4 x = ldE(Lb, B2+i*32+v); s += x*x; }
    stE(Lb, INVO+c, sqrt4(s));
  }
  __syncthreads();
  {
    const int w = c>>6, l = c&63;   // wave w <-> node w
    float s=0.f, s2=0.f, x;
    x = bfh(Lb16[(INVO+l)*4+w]);      s+=x; s2+=x*x;
    x = bfh(Lb16[(INVO+64+l)*4+w]);   s+=x; s2+=x*x;
    x = bfh(Lb16[(INVO+128+l)*4+w]);  s+=x; s2+=x*x;
    if (l < 32) { x = bfh(Lb16[(INVO+192+l)*4+w]); s+=x; s2+=x*x; }
    #pragma unroll
    for (int off=32; off>=1; off>>=1) {
      s  += __shfl_xor(s,  off, 64);
      s2 += __shfl_xor(s2, off, 64);
    }
    if (l==0) {
      const float m = s*(1.f/224.f);
      ((float*)&sRed[0])[w] = m;
      ((float*)&sRed[1])[w] = rsqrtf(s2*(1.f/224.f) - m*m + 1e-5f);
    }
  }
  __syncthreads();
  if (c < TMUL) {
    const f32x4 x = ldE(Lb, INVO+c);
    const f32x4 vn = (x - sRed[0])*sRed[1];
    FT16[0*FSTR+c]=f2bf(vn.x); FT16[1*FSTR+c]=f2bf(vn.y);
    FT16[2*FSTR+c]=f2bf(vn.z); FT16[3*FSTR+c]=f2bf(vn.w);
  }
  __syncthreads();                  // vn fragment buffer complete (rows 4-15 garbage: unread D rows)

  const int wv = c>>6, ln = c&63;
  // ---- MLP1: vn @ wb1 ----
  f32x4 m0={}, m1={}, m2={}, m3={};
  #pragma unroll
  for (int kt=0; kt<7; ++kt) {
    const short8 A = *(const short8*)&FT16[(ln&15)*FSTR + kt*32 + (ln>>4)*8];
    { const short8 B = *(const short8*)&wb1[((kt*14 + wv    )*64 + ln)*8];
      m0 = __builtin_amdgcn_mfma_f32_16x16x32_bf16(A, B, m0, 0, 0, 0); }
    { const short8 B = *(const short8*)&wb1[((kt*14 + wv + 4)*64 + ln)*8];
      m1 = __builtin_amdgcn_mfma_f32_16x16x32_bf16(A, B, m1, 0, 0, 0); }
    { const short8 B = *(const short8*)&wb1[((kt*14 + wv + 8)*64 + ln)*8];
      m2 = __builtin_amdgcn_mfma_f32_16x16x32_bf16(A, B, m2, 0, 0, 0); }
    if (wv < 2) {
      const short8 B = *(const short8*)&wb1[((kt*14 + wv +12)*64 + ln)*8];
      m3 = __builtin_amdgcn_mfma_f32_16x16x32_bf16(A, B, m3, 0, 0, 0);
    }
  }
  __syncthreads();                  // all reads of FT(vn) done
  if (ln < 16) {
    { const int ch=(wv   )*16+ln; const f32x4 h=silu4(m0+gb1[ch]);
      FT16[0*FSTR+ch]=f2bf(h.x); FT16[1*FSTR+ch]=f2bf(h.y); FT16[2*FSTR+ch]=f2bf(h.z); FT16[3*FSTR+ch]=f2bf(h.w); }
    { const int ch=(wv+4 )*16+ln; const f32x4 h=silu4(m1+gb1[ch]);
      FT16[0*FSTR+ch]=f2bf(h.x); FT16[1*FSTR+ch]=f2bf(h.y); FT16[2*FSTR+ch]=f2bf(h.z); FT16[3*FSTR+ch]=f2bf(h.w); }
    { const int ch=(wv+8 )*16+ln; const f32x4 h=silu4(m2+gb1[ch]);
      FT16[0*FSTR+ch]=f2bf(h.x); FT16[1*FSTR+ch]=f2bf(h.y); FT16[2*FSTR+ch]=f2bf(h.z); FT16[3*FSTR+ch]=f2bf(h.w); }
    if (wv < 2) {
      const int ch=(wv+12)*16+ln; const f32x4 h=silu4(m3+gb1[ch]);
      FT16[0*FSTR+ch]=f2bf(h.x); FT16[1*FSTR+ch]=f2bf(h.y); FT16[2*FSTR+ch]=f2bf(h.z); FT16[3*FSTR+ch]=f2bf(h.w); }
  }
  __syncthreads();                  // FT now holds H
  // ---- MLP2: H @ wb2 ----
  f32x4 g0={}, g1={}, g2={}, g3={};
  #pragma unroll
  for (int kt=0; kt<7; ++kt) {
    const short8 A = *(const short8*)&FT16[(ln&15)*FSTR + kt*32 + (ln>>4)*8];
    { const short8 B = *(const short8*)&wb2[((kt*14 + wv    )*64 + ln)*8];
      g0 = __builtin_amdgcn_mfma_f32_16x16x32_bf16(A, B, g0, 0, 0, 0); }
    { const short8 B = *(const short8*)&wb2[((kt*14 + wv + 4)*64 + ln)*8];
      g1 = __builtin_amdgcn_mfma_f32_16x16x32_bf16(A, B, g1, 0, 0, 0); }
    { const short8 B = *(const short8*)&wb2[((kt*14 + wv + 8)*64 + ln)*8];
      g2 = __builtin_amdgcn_mfma_f32_16x16x32_bf16(A, B, g2, 0, 0, 0); }
    if (wv < 2) {
      const short8 B = *(const short8*)&wb2[((kt*14 + wv +12)*64 + ln)*8];
      g3 = __builtin_amdgcn_mfma_f32_16x16x32_bf16(A, B, g3, 0, 0, 0);
    }
  }
  if (ln < 16) {                    // G -> node-minor
    { const int ch=(wv   )*16+ln; stE(Lb, GO+ch, silu4(g0+gb2[ch])); }
    { const int ch=(wv+4 )*16+ln; stE(Lb, GO+ch, silu4(g1+gb2[ch])); }
    { const int ch=(wv+8 )*16+ln; stE(Lb, GO+ch, silu4(g2+gb2[ch])); }
    if (wv < 2) { const int ch=(wv+12)*16+ln; stE(Lb, GO+ch, silu4(g3+gb2[ch])); }
  }
  __syncthreads();                  // G visible to all threads
}

// ------------------------- CG rows, groups B and C (VALU t + Wigner -> frag C writes) -------------------------
__device__ __forceinline__ void cg_rowB(const int r, const float* __restrict__ wt,
                                        const W3Pack& W, uint* __restrict__ Lb,
                                        ushort* __restrict__ C0f, ushort* __restrict__ C1f,
                                        ushort* __restrict__ C2f)
{
  f32x4 tb[3];
  tstageB<3,64,64>(wt + 28672 + r, 288, Lb, P1O, tb);
  if (r < 128) {                       // p2 (0,1,1): C1 col r
    const f32x4 f = ldE(Lb, F0O+r);
    #pragma unroll
    for (int k=0;k<3;++k) {
      f32x4 s = tb[0]*W.v[1+0*3+k] + tb[1]*W.v[1+1*3+k] + tb[2]*W.v[1+2*3+k];
      stF(C1f, 288, k*4, r, f*s);
    }
  } else if (r < 192) {                // p5 (1,1,0): C0 col 128+u
    const int u=r-128;
    f32x4 y = {};
    #pragma unroll
    for (int i=0;i<3;++i) {
      f32x4 s = tb[0]*W.v[44+i*3+0] + tb[1]*W.v[44+i*3+1] + tb[2]*W.v[44+i*3+2];
      y += ldE(Lb, F1O+i*64+u)*s;
    }
    stF(C0f, 224, 0, 128+u, y);
  } else if (r < 256) {                // p6 (1,1,2): C2 col 128+u
    const int u=r-192;
    f32x4 f[3];
    #pragma unroll
    for (int i=0;i<3;++i) f[i]=ldE(Lb, F1O+i*64+u);
    #pragma unroll
    for (int k=0;k<5;++k) {
      f32x4 y = {};
      #pragma unroll
      for (int i=0;i<3;++i) {
        f32x4 s = tb[0]*W.v[53+(i*3+0)*5+k] + tb[1]*W.v[53+(i*3+1)*5+k] + tb[2]*W.v[53+(i*3+2)*5+k];
        y += f[i]*s;
      }
      stF(C2f, 256, k*4, 128+u, y);
    }
  } else {                             // p9 (2,1,1): C1 col 256+u
    const int u=r-256;
    f32x4 f[5];
    #pragma unroll
    for (int i=0;i<5;++i) f[i]=ldE(Lb, F2O+i*32+u);
    #pragma unroll
    for (int k=0;k<3;++k) {
      f32x4 y = {};
      #pragma unroll
      for (int i=0;i<5;++i) {
        f32x4 s = tb[0]*W.v[168+(i*3+0)*3+k] + tb[1]*W.v[168+(i*3+1)*3+k] + tb[2]*W.v[168+(i*3+2)*3+k];
        y += f[i]*s;
      }
      stF(C1f, 288, k*4, 256+u, y);
    }
  }
}

__device__ __forceinline__ void cg_rowC(const int r, const float* __restrict__ wt,
                                        const W3Pack& W, uint* __restrict__ Lb,
                                        ushort* __restrict__ C0f, ushort* __restrict__ C1f,
                                        ushort* __restrict__ C2f)
{
  f32x4 tc[5];
  tstageB<5,32,32>(wt + 47104 + r, 256, Lb, P2O, tc);
  if (r < 128) {                       // p3 (0,2,2): C2 col r
    const f32x4 f = ldE(Lb, F0O+r);
    #pragma unroll
    for (int k=0;k<5;++k) {
      f32x4 s = {};
      #pragma unroll
      for (int j=0;j<5;++j) s += tc[j]*W.v[10+j*5+k];
      stF(C2f, 256, k*4, r, f*s);
    }
  } else if (r < 192) {                // p7 (1,2,1): C1 col 192+u
    const int u=r-128;
    f32x4 f[3];
    #pragma unroll
    for (int i=0;i<3;++i) f[i]=ldE(Lb, F1O+i*64+u);
    #pragma unroll
    for (int k=0;k<3;++k) {
      f32x4 y = {};
      #pragma unroll
      for (int i=0;i<3;++i) {
        f32x4 s = {};
        #pragma unroll
        for (int j=0;j<5;++j) s += tc[j]*W.v[98+(i*5+j)*3+k];
        y += f[i]*s;
      }
      stF(C1f, 288, k*4, 192+u, y);
    }
  } else if (r < 224) {                // p10 (2,2,0): C0 col 192+u
    const int u=r-192;
    f32x4 y = {};
    #pragma unroll
    for (int i=0;i<5;++i) {
      f32x4 s = {};
      #pragma unroll
      for (int j=0;j<5;++j) s += tc[j]*W.v[213+i*5+j];
      y += ldE(Lb, F2O+i*32+u)*s;
    }
    stF(C0f, 224, 0, 192+u, y);
  } else {                             // p11 (2,2,2): C2 col 224+u
    const int u=r-224;
    f32x4 f[5];
    #pragma unroll
    for (int i=0;i<5;++i) f[i]=ldE(Lb, F2O+i*32+u);
    #pragma unroll
    for (int k=0;k<5;++k) {
      f32x4 y = {};
      #pragma unroll
      for (int i=0;i<5;++i) {
        f32x4 s = {};
        #pragma unroll
        for (int j=0;j<5;++j) s += tc[j]*W.v[238+(i*5+j)*5+k];
        y += f[i]*s;
      }
      stF(C2f, 256, k*4, 224+u, y);
    }
  }
}

// ------------------------- fused kernel -------------------------
__global__ __launch_bounds__(256, 3) void fused4(
  const float* __restrict__ feat,
  const float* __restrict__ pgb1, const float* __restrict__ pgb2,
  const float* __restrict__ wt, const ushort* __restrict__ wb, const ushort* __restrict__ wf,
  const float* __restrict__ qgb1, const float* __restrict__ qgb2,
  float* __restrict__ outp, const W3Pack W)
{
  __shared__ uint LbU[NMSZ*2];        // 16896 B node-minor
  __shared__ ushort BF[16384];        // 32768 B fragment staging
  __shared__ f32x4 sRed[2];
  uint* Lb = LbU;
  ushort* Lb16 = (ushort*)LbU;
  ushort* C0f = BF;
  ushort* C1f = BF + 3584;
  ushort* C2f = BF + 8192;
  ushort* FT16 = BF;                  // overlays C0f/C1f head (disjoint lifetime)
  ushort* F0f = BF + 8192;            // overlays C2f (disjoint lifetime)
  ushort* F1f = BF + 10240;
  ushort* F2f = BF + 11264;
  const int c = threadIdx.x;
  const int wv = c>>6, ln = c&63;
  const size_t gbase = (size_t)blockIdx.x * (FEAT_DIM*NB);

  // ---- load + de-interleave: node-minor NM + A-fragment Ff ----
  for (int t=c; t<FEAT_DIM*NB; t+=256) {
    const float val = feat[gbase + t];
    const int nb = t / FEAT_DIM;
    const int ch = t - nb*FEAT_DIM;
    const ushort b = f2bf(val);
    if (ch < 128) {
      Lb16[(F0O+ch)*4 + nb] = b;
      F0f[nb*128 + ch] = b;
    } else if (ch < 320) {
      const int q = ch-128; const int u = q/3; const int i = q-u*3;
      Lb16[(F1O + i*64 + u)*4 + nb] = b;
      F1f[(i*4+nb)*64 + u] = b;
    } else {
      const int q = ch-320; const int u = q/5; const int i = q-u*5;
      Lb16[(F2O + i*32 + u)*4 + nb] = b;
      if (i < 4) F2f[(i*4+nb)*32 + u] = b;
      else       F2f[(16+nb)*32 + u] = b;
    }
  }
  __syncthreads();

  // ---- pre-linear via MFMA ----
  {
    // l0: [4n x 128] @ w0f -> P0 ; ct = 2wv, 2wv+1
    #pragma unroll
    for (int half=0; half<2; ++half) {
      const int ct = wv*2+half;
      f32x4 acc = {};
      #pragma unroll
      for (int kt=0; kt<4; ++kt) {
        const short8 A = *(const short8*)&F0f[(ln&15)*128 + kt*32 + (ln>>4)*8];
        const short8 B = *(const short8*)&wf[((kt*8+ct)*64+ln)*8];
        acc = __builtin_amdgcn_mfma_f32_16x16x32_bf16(A,B,acc,0,0,0);
      }
      if (ln < 16) stE(Lb, P0O + ct*16 + ln, acc);
    }
    // l1: rows (i*4+n) x K=64 -> P1 ; ct = wv
    {
      f32x4 acc = {};
      #pragma unroll
      for (int kt=0; kt<2; ++kt) {
        const short8 A = *(const short8*)&F1f[(ln&15)*64 + kt*32 + (ln>>4)*8];
        const short8 B = *(const short8*)&wf[16384 + ((kt*4+wv)*64+ln)*8];
        acc = __builtin_amdgcn_mfma_f32_16x16x32_bf16(A,B,acc,0,0,0);
      }
      if (ln < 48) stE(Lb, P1O + (ln>>4)*64 + wv*16 + (ln&15), acc);
    }
    // l2: two 16-row tiles x K=32 -> P2 ; unit wv = (tile, ct)
    {
      const int tile = wv>>1, ct = wv&1;
      const short8 A = *(const short8*)&F2f[(tile*16+(ln&15))*32 + (ln>>4)*8];
      const short8 B = *(const short8*)&wf[20480 + (ct*64+ln)*8];
      f32x4 acc = {};
      acc = __builtin_amdgcn_mfma_f32_16x16x32_bf16(A,B,acc,0,0,0);
      if (tile==0) stE(Lb, P2O + (ln>>4)*32 + ct*16 + (ln&15), acc);
      else if (ln < 16) stE(Lb, P2O + 128 + ct*16 + ln, acc);
    }
  }
  __syncthreads();

  // ---- pre normgate (MFMA MLPs) + gate P in place ----
  normgateB(Lb, Lb16, FT16, sRed, c, P0O, P1O, P2O, wb, pgb1, wb+50176, pgb2);
  if (c < 128) {
    stE(Lb, P0O+c, ldE(Lb,P0O+c)*ldE(Lb,GO+c));
  } else if (c < 192) {
    const int v=c-128; const f32x4 g=ldE(Lb,GO+c);
    #pragma unroll
    for (int i=0;i<3;++i) stE(Lb, P1O+i*64+v, ldE(Lb,P1O+i*64+v)*g);
  } else if (c < 224) {
    const int v=c-192; const f32x4 g=ldE(Lb,GO+c);
    #pragma unroll
    for (int i=0;i<5;++i) stE(Lb, P2O+i*32+v, ldE(Lb,P2O+i*32+v)*g);
  }
  __syncthreads();   // P gated

  // ---- CG coupling: group A (thread=row; VALU t) -> frag C writes ----
  if (c < 224) {
    const f32x4 tA = matcolB<128>(wt, 224, c, Lb, P0O);
    if (c < 128) {                     // p1 (0,0,0): C0 col c
      stF(C0f, 224, 0, c, ldE(Lb,F0O+c)*tA*W.v[0]);
    } else if (c < 192) {              // p4 (1,0,1): C1 col 128+u
      const int u=c-128;
      const f32x4 f0=ldE(Lb,F1O+u), f1=ldE(Lb,F1O+64+u), f2=ldE(Lb,F1O+128+u);
      #pragma unroll
      for (int k=0;k<3;++k)
        stF(C1f, 288, k*4, 128+u, tA*(f0*W.v[35+k] + f1*W.v[38+k] + f2*W.v[41+k]));
    } else {                           // p8 (2,0,2): C2 col 192+u
      const int u=c-192;
      f32x4 f[5];
      #pragma unroll
      for (int i=0;i<5;++i) f[i]=ldE(Lb,F2O+i*32+u);
      #pragma unroll
      for (int k=0;k<5;++k) {
        f32x4 y = {};
        #pragma unroll
        for (int i=0;i<5;++i) y += f[i]*W.v[143+i*5+k];
        stF(C2f, 256, k*4, 192+u, tA*y);
      }
    }
  }
  cg_rowB(c, wt, W, Lb, C0f, C1f, C2f);
  if (c >= 224) cg_rowB(c+32, wt, W, Lb, C0f, C1f, C2f);
  cg_rowC(c, wt, W, Lb, C0f, C1f, C2f);
  __syncthreads();

  // ---- post-linear via MFMA: C frags @ pw frags -> Q node-minor ----
  {
    // l0: A=C0f [4n x 224], N=128 ; ct = 2wv, 2wv+1
    #pragma unroll
    for (int half=0; half<2; ++half) {
      const int ct = wv*2+half;
      f32x4 acc = {};
      #pragma unroll
      for (int kt=0; kt<7; ++kt) {
        const short8 A = *(const short8*)&C0f[(ln&15)*224 + kt*32 + (ln>>4)*8];
        const short8 B = *(const short8*)&wf[21504 + ((kt*8+ct)*64+ln)*8];
        acc = __builtin_amdgcn_mfma_f32_16x16x32_bf16(A,B,acc,0,0,0);
      }
      if (ln < 16) stE(Lb, Q0O + ct*16 + ln, acc);
    }
    // l1: A=C1f rows (i*4+n) x K=288, N=64 ; ct = wv
    {
      f32x4 acc = {};
      #pragma unroll
      for (int kt=0; kt<9; ++kt) {
        const short8 A = *(const short8*)&C1f[(ln&15)*288 + kt*32 + (ln>>4)*8];
        const short8 B = *(const short8*)&wf[50176 + ((kt*4+wv)*64+ln)*8];
        acc = __builtin_amdgcn_mfma_f32_16x16x32_bf16(A,B,acc,0,0,0);
      }
      if (ln < 48) stE(Lb, Q1O + (ln>>4)*64 + wv*16 + (ln&15), acc);
    }
    // l2: A=C2f two tiles x K=256, N=32 ; unit wv = (tile, ct)
    {
      const int tile = wv>>1, ct = wv&1;
      f32x4 acc = {};
      #pragma unroll
      for (int kt=0; kt<8; ++kt) {
        const short8 A = *(const short8*)&C2f[(tile*16+(ln&15))*256 + kt*32 + (ln>>4)*8];
        const short8 B = *(const short8*)&wf[68608 + ((kt*2+ct)*64+ln)*8];
        acc = __builtin_amdgcn_mfma_f32_16x16x32_bf16(A,B,acc,0,0,0);
      }
      if (tile==0) stE(Lb, Q2O + (ln>>4)*32 + ct*16 + (ln&15), acc);
      else if (ln < 16) stE(Lb, Q2O + 128 + ct*16 + ln, acc);
    }
  }
  __syncthreads();

  // ---- post normgate (MFMA MLPs) ----
  normgateB(Lb, Lb16, FT16, sRed, c, Q0O, Q1O, Q2O, wb+100352, qgb1, wb+150528, qgb2);

  // ---- final: out = feat(f32 re-read) + pre_gated + post*G ----
  for (int t=c; t<FEAT_DIM*NB; t+=256) {
    const int nb = t / FEAT_DIM;
    const int ch = t - nb*FEAT_DIM;
    float pre, q, g;
    if (ch < 128) {
      pre = bfh(Lb16[(P0O+ch)*4+nb]);
      q   = bfh(Lb16[(Q0O+ch)*4+nb]);
      g   = bfh(Lb16[(GO+ch)*4+nb]);
    } else if (ch < 320) {
      const int qq=ch-128; const int u=qq/3; const int o=(qq-u*3)*64+u;
      pre = bfh(Lb16[(P1O+o)*4+nb]);
      q   = bfh(Lb16[(Q1O+o)*4+nb]);
      g   = bfh(Lb16[(GO+128+u)*4+nb]);
    } else {
      const int qq=ch-320; const int u=qq/5; const int o=(qq-u*5)*32+u;
      pre = bfh(Lb16[(P2O+o)*4+nb]);
      q   = bfh(Lb16[(Q2O+o)*4+nb]);
      g   = bfh(Lb16[(GO+192+u)*4+nb]);
    }
    outp[gbase + t] = feat[gbase + t] + pre + q*g;
  }
}

// ------------------------- launch -------------------------
extern "C" void kernel_launch(void* const* d_in, const int* in_sizes, int n_in,
                              void* d_out, int out_size, void* d_ws, size_t ws_size,
                              hipStream_t stream)
{
  (void)in_sizes; (void)n_in; (void)out_size; (void)ws_size;
  const float* feat  = (const float*)d_in[0];
  const float* prw0  = (const float*)d_in[1];
  const float* prw1  = (const float*)d_in[2];
  const float* prw2  = (const float*)d_in[3];
  const float* pngw1 = (const float*)d_in[4];
  const float* pngb1 = (const float*)d_in[5];
  const float* pngw2 = (const float*)d_in[6];
  const float* pngb2 = (const float*)d_in[7];
  const float* tpw   = (const float*)d_in[8];
  const float* pow0  = (const float*)d_in[9];
  const float* pow1  = (const float*)d_in[10];
  const float* pow2  = (const float*)d_in[11];
  const float* qngw1 = (const float*)d_in[12];
  const float* qngb1 = (const float*)d_in[13];
  const float* qngw2 = (const float*)d_in[14];
  const float* qngb2 = (const float*)d_in[15];

  float*  wt = (float*)d_ws;                                   // 55296 f32 (221184 B)
  ushort* wb = (ushort*)((char*)d_ws + 221184);                // 4*50176 bf16 gate MLPs (401408 B)
  ushort* wf = (ushort*)((char*)d_ws + 221184 + 401408);       // 76800 bf16 pre/post linear frags

  W3Pack W = build_w3();               // host-only, identical every call

  prep_tpw<<<dim3(216), dim3(256), 0, stream>>>(tpw, wt);
  prep_mlp<<<dim3(784), dim3(256), 0, stream>>>(pngw1, pngw2, qngw1, qngw2, wb);
  prep_lin<<<dim3(300), dim3(256), 0, stream>>>(prw0, prw1, prw2, pow0, pow1, pow2, wf);

  fused4<<<dim3(N_NODES/NB), dim3(256), 0, stream>>>(
      feat, pngb1, pngb2, wt, wb, wf, qngb1, qngb2,
      (float*)d_out, W);
}